// Round 9
// baseline (1975.558 us; speedup 1.0000x reference)
//
#include <hip/hip_runtime.h>
#include <hip/hip_bf16.h>
#include <cstdint>
#include <cstddef>

// ---------------------------------------------------------------------------
// IPAttnProcessor: out = (softmax(QK^T)V + softmax(QKip^T)Vip) @ Wo + bo + residual
// B=8 SQ=4096 C=1280 CAD=2048 H=20 D=64 TXT=77 NT=4 IP_SCALE=1
// Big GEMMs: 256^2 tile, BK=32, 64KB dbuf-2 LDS -> 2 blocks/CU (m97-style
// 2-barrier loop; cross-block overlap does the latency hiding, m114).
// LDS-packed bf16 epilogue (2x128-row passes). Merged utility launches.
// ---------------------------------------------------------------------------

typedef __bf16 bf16_t;
typedef __bf16 bf16x8 __attribute__((ext_vector_type(8)));
typedef __bf16 bf16x4 __attribute__((ext_vector_type(4)));
typedef float  f32x4  __attribute__((ext_vector_type(4)));
typedef unsigned int u32x4 __attribute__((ext_vector_type(4)));

using as3_void  = __attribute__((address_space(3))) void;
using as1_cvoid = const __attribute__((address_space(1))) void;

#define TXT_ 77

__device__ __forceinline__ bf16x8 ld16(const void* p) {
  u32x4 v = *(const u32x4*)p;
  return __builtin_bit_cast(bf16x8, v);
}

// ---------------------------------------------------------------------------
// Big GEMM: C[M,N] = A[M,K] @ Bt[N,K]^T. 256x256 tile, BK=32, 512 thr (8 waves
// = 2M x 4N, per-wave 128x64, acc[8][4]). LDS 64KB: 2 bufs x (A 16KB + B 16KB)
// -> 2 blocks/CU (4 waves/SIMD). m97 loop: __syncthreads (drains vmcnt) then
// stage(t+1) into buf^1; frags + 32 MFMA from buf. Staging/read swizzle
// byte-identical to r4 (verified 0 bank conflicts).
// EPI=0: LDS-packed bf16 epilogue, two 128-row passes (full-line 512B stores).
// EPI=2: f32 + bias[col] + bf16 residual (64B stores, no amp).
// ---------------------------------------------------------------------------
template <int EPI>
__global__ __launch_bounds__(512, 4)
void gemm256(const bf16_t* __restrict__ A, const bf16_t* __restrict__ Bt,
             void* __restrict__ Cout, int ntn, int N, int K,
             const float* __restrict__ bias, const void* __restrict__ residual)
{
  __shared__ __align__(16) char smem[2][32768]; // per buf: A @0 16KB, B @16KB
  const int tid = threadIdx.x, lane = tid & 63, wid = tid >> 6;
  const int wm = wid >> 2, wn = wid & 3;

  const int nwg = gridDim.x;
  int g = blockIdx.x;
  if ((nwg & 7) == 0) g = (blockIdx.x & 7) * (nwg >> 3) + (blockIdx.x >> 3);
  const long bm = (long)(g / ntn) * 256;
  const long bn = (long)(g % ntn) * 256;
  const int NTk = K >> 5;

  // staging: 1KB unit = 16 rows x 64B; lane -> row (lane>>2), phys chunk lane&3
  // holding logical chunk (lane&3)^((lane>>3)&3)  [r4-verified, 0 conflicts]
  const int srow = lane >> 2;
  const int scol = ((lane & 3) ^ ((lane >> 3) & 3)) * 8;

  auto stage = [&](int buf, int t) {
    const long k0 = (long)t << 5;
#pragma unroll
    for (int j = 0; j < 2; ++j) {
      const int ci = j * 8 + wid;
      const bf16_t* ga = A + (bm + ci * 16 + srow) * (long)K + k0 + scol;
      __builtin_amdgcn_global_load_lds((as1_cvoid*)ga,
          (as3_void*)(&smem[buf][ci * 1024]), 16, 0, 0);
      const bf16_t* gb = Bt + (bn + ci * 16 + srow) * (long)K + k0 + scol;
      __builtin_amdgcn_global_load_lds((as1_cvoid*)gb,
          (as3_void*)(&smem[buf][16384 + ci * 1024]), 16, 0, 0);
    }
  };

  const int l15 = lane & 15, kq = lane >> 4;
  const int rc16 = (kq ^ ((l15 >> 1) & 3)) << 4; // read-side swizzled 16B chunk

  f32x4 acc[8][4] = {};
  bf16x8 afr[4], bfr[4];

  stage(0, 0);
  int cur = 0;
  for (int t = 0; t < NTk; ++t) {
    __syncthreads(); // compiler emits vmcnt(0)+lgkmcnt(0) drain: buf[cur] ready
    if (t + 1 < NTk) stage(cur ^ 1, t + 1);
    const char* sa = smem[cur];
    const char* sb = smem[cur] + 16384;
#pragma unroll
    for (int n = 0; n < 4; ++n)
      bfr[n] = ld16(sb + (wn * 64 + n * 16 + l15) * 64 + rc16);
#pragma unroll
    for (int m = 0; m < 4; ++m)
      afr[m] = ld16(sa + (wm * 128 + m * 16 + l15) * 64 + rc16);
#pragma unroll
    for (int m = 0; m < 4; ++m)
#pragma unroll
      for (int n = 0; n < 4; ++n)
        acc[m][n] = __builtin_amdgcn_mfma_f32_16x16x32_bf16(afr[m], bfr[n], acc[m][n], 0, 0, 0);
#pragma unroll
    for (int m = 0; m < 4; ++m)
      afr[m] = ld16(sa + (wm * 128 + (m + 4) * 16 + l15) * 64 + rc16);
#pragma unroll
    for (int m = 0; m < 4; ++m)
#pragma unroll
      for (int n = 0; n < 4; ++n)
        acc[m + 4][n] = __builtin_amdgcn_mfma_f32_16x16x32_bf16(afr[m], bfr[n], acc[m + 4][n], 0, 0, 0);
    cur ^= 1;
  }

  const int orow0 = (lane >> 4) << 2;
  if constexpr (EPI == 0) {
    // LDS-packed epilogue in two 128-row passes (64KB = [128][256] bf16).
    // Pass h: waves with wm==h deposit their acc; all threads sweep out rows
    // as 512B-contiguous full lines (32 lanes x 16B).
    bf16_t* cl = (bf16_t*)smem;
    const int rr = tid >> 5, cc = tid & 31;
#pragma unroll
    for (int h = 0; h < 2; ++h) {
      __syncthreads();
      if (wm == h) {
#pragma unroll
        for (int m = 0; m < 8; ++m)
#pragma unroll
          for (int n = 0; n < 4; ++n)
#pragma unroll
            for (int r = 0; r < 4; ++r)
              cl[(m * 16 + orow0 + r) * 256 + wn * 64 + n * 16 + l15] =
                  (bf16_t)acc[m][n][r];
      }
      __syncthreads();
#pragma unroll
      for (int s = 0; s < 8; ++s) {
        const int row = s * 16 + rr;
        const u32x4 v = *(const u32x4*)(cl + row * 256 + cc * 8);
        *(u32x4*)((bf16_t*)Cout + (bm + h * 128 + row) * (long)N + bn + cc * 8) = v;
      }
    }
  } else {
#pragma unroll
    for (int m = 0; m < 8; ++m) {
#pragma unroll
      for (int n = 0; n < 4; ++n) {
        const long col = bn + wn * 64 + n * 16 + l15;
#pragma unroll
        for (int r = 0; r < 4; ++r) {
          const long row = bm + wm * 128 + m * 16 + orow0 + r;
          ((float*)Cout)[row * N + col] =
              acc[m][n][r] + bias[col] +
              (float)((const bf16_t*)residual)[row * N + col];
        }
      }
    }
  }
}

// ---------------------------------------------------------------------------
// Merged small GEMM (m97 128^2 structure): blocks 0-99 -> K|V proj (M=640),
// blocks 100-119 -> Kip|Vip proj (M=128). N=2560, K=2048, ntn=20 for both.
// ---------------------------------------------------------------------------
__global__ __launch_bounds__(256, 4)
void gemm_small(const bf16_t* __restrict__ A0, const bf16_t* __restrict__ B0,
                bf16_t* __restrict__ C0,
                const bf16_t* __restrict__ A1, const bf16_t* __restrict__ B1,
                bf16_t* __restrict__ C1)
{
  __shared__ __align__(16) char smem[2][16384];
  const int tid  = threadIdx.x;
  const int lane = tid & 63;
  const int wid  = tid >> 6;
  const int wm = wid >> 1, wn = wid & 1;

  const bf16_t *A, *Bt;
  bf16_t* Cout;
  int g = blockIdx.x;
  if (g < 100) { A = A0; Bt = B0; Cout = C0; }
  else         { A = A1; Bt = B1; Cout = C1; g -= 100; }
  const int ntn = 20, N = 2560, K = 2048;

  const long bm = (long)(g / ntn) * 128;
  const long bn = (long)(g % ntn) * 128;

  f32x4 acc[4][4] = {};

  const int srow = lane >> 2;
  const int skb  = (lane & 3) ^ (((lane >> 2) ^ (lane >> 4)) & 3);
  const int NT = K >> 5;

  auto stage = [&](int buf, int kt) {
    const int k0 = kt << 5;
#pragma unroll
    for (int cc = 0; cc < 2; ++cc) {
      const int c = wid + cc * 4;
      const bf16_t* ga = A + (bm + c * 16 + srow) * (long)K + (k0 + skb * 8);
      __builtin_amdgcn_global_load_lds((as1_cvoid*)ga,
                                       (as3_void*)(&smem[buf][c * 1024]), 16, 0, 0);
      const bf16_t* gb = Bt + (bn + c * 16 + srow) * (long)K + (k0 + skb * 8);
      __builtin_amdgcn_global_load_lds((as1_cvoid*)gb,
                                       (as3_void*)(&smem[buf][8192 + c * 1024]), 16, 0, 0);
    }
  };

  const int rkb    = (((lane >> 4) ^ (lane & 3) ^ ((lane >> 2) & 3)) & 3) << 4;
  const int rrow_a = wm * 64 + (lane & 15);
  const int rrow_b = wn * 64 + (lane & 15);

  stage(0, 0);
  int cur = 0;
  for (int t = 0; t < NT; ++t) {
    __syncthreads();
    if (t + 1 < NT) stage(cur ^ 1, t + 1);
    const char* sa = smem[cur];
    const char* sb = smem[cur] + 8192;
    bf16x8 af[4], bfv[4];
#pragma unroll
    for (int m = 0; m < 4; ++m)
      af[m] = ld16(sa + (rrow_a + m * 16) * 64 + rkb);
#pragma unroll
    for (int n = 0; n < 4; ++n)
      bfv[n] = ld16(sb + (rrow_b + n * 16) * 64 + rkb);
#pragma unroll
    for (int m = 0; m < 4; ++m)
#pragma unroll
      for (int n = 0; n < 4; ++n)
        acc[m][n] = __builtin_amdgcn_mfma_f32_16x16x32_bf16(af[m], bfv[n], acc[m][n], 0, 0, 0);
    cur ^= 1;
  }

  const int orow0 = wm * 64 + ((lane >> 4) << 2);
  const int ocol0 = wn * 64 + (lane & 15);
#pragma unroll
  for (int m = 0; m < 4; ++m)
#pragma unroll
    for (int n = 0; n < 4; ++n) {
      const long col = bn + ocol0 + n * 16;
#pragma unroll
      for (int r = 0; r < 4; ++r)
        Cout[(bm + orow0 + m * 16 + r) * (long)N + col] = (bf16_t)acc[m][n][r];
    }
}

// ---------------------------------------------------------------------------
// Fused attention (unchanged; writes in-place over Q).
// ---------------------------------------------------------------------------
__global__ __launch_bounds__(256, 3)
void attn_fused(const bf16_t* __restrict__ q, const bf16_t* __restrict__ kvt,
                const bf16_t* __restrict__ kvip, bf16_t* __restrict__ outp)
{
  __shared__ __align__(16) bf16_t K_lds[80 * 64];
  __shared__ __align__(16) bf16_t Kip_lds[16 * 64];
  __shared__ __align__(16) bf16_t Vt_lds[64 * 128];
  __shared__ __align__(16) bf16_t P_lds[4][16 * 128];

  const int tid = threadIdx.x, lane = tid & 63, wid = tid >> 6;
  const int h = blockIdx.y, b = blockIdx.z;
  const int kvcol = h << 6;

  for (int idx = tid; idx < 640; idx += 256) {
    const int j = idx >> 3, c = idx & 7;
    bf16x8 v = {};
    if (j < TXT_) v = ld16(kvt + (long)(b * 80 + j) * 2560 + kvcol + c * 8);
    *(bf16x8*)((char*)K_lds + j * 128 + ((c ^ (j & 7)) << 4)) = v;
  }
  if (tid < 128) {
    const int j = tid >> 3, c = tid & 7;
    bf16x8 v = {};
    if (j < 4) v = ld16(kvip + (long)(b * 4 + j) * 2560 + kvcol + c * 8);
    *(bf16x8*)((char*)Kip_lds + j * 128 + ((c ^ (j & 7)) << 4)) = v;
  }
  for (int idx = tid; idx < 1024; idx += 256) {
    const int key = idx >> 3, c = idx & 7;
    bf16x8 v = {};
    if (key < TXT_)
      v = ld16(kvt + (long)(b * 80 + key) * 2560 + 1280 + kvcol + c * 8);
    else if (key >= 96 && key < 100)
      v = ld16(kvip + (long)(b * 4 + key - 96) * 2560 + 1280 + kvcol + c * 8);
#pragma unroll
    for (int e = 0; e < 8; ++e) {
      const int d = c * 8 + e;
      *(bf16_t*)((char*)Vt_lds + d * 256 + ((key * 2) ^ ((d & 7) << 4))) = v[e];
    }
  }
  for (int idx = tid; idx < 1024; idx += 256)
    *(bf16x8*)((char*)P_lds + idx * 16) = (bf16x8){};
  __syncthreads();

  const int l15 = lane & 15, hi = lane >> 4;
  const int dblk = hi << 3;
  const int prow0 = hi << 2;
  const float scale = 0.125f;
  char* const pw = (char*)P_lds[wid];

  const long qrow0 = (long)b * 4096 + ((long)blockIdx.x << 8) + (wid << 6);
  bf16x8 qf[4][2];
#pragma unroll
  for (int ms = 0; ms < 4; ++ms) {
    const bf16_t* qp = q + (qrow0 + ms * 16 + l15) * 1280 + kvcol;
    qf[ms][0] = ld16(qp + dblk);
    qf[ms][1] = ld16(qp + 32 + dblk);
  }

#pragma unroll
  for (int ms = 0; ms < 4; ++ms) {
    f32x4 sc[5];
#pragma unroll
    for (int t = 0; t < 5; ++t) {
      const int j = (t << 4) + l15;
      const bf16x8 k0 = ld16((char*)K_lds + j * 128 + ((hi ^ (j & 7)) << 4));
      const bf16x8 k1 = ld16((char*)K_lds + j * 128 + (((4 + hi) ^ (j & 7)) << 4));
      f32x4 z = {0.f, 0.f, 0.f, 0.f};
      z = __builtin_amdgcn_mfma_f32_16x16x32_bf16(qf[ms][0], k0, z, 0, 0, 0);
      z = __builtin_amdgcn_mfma_f32_16x16x32_bf16(qf[ms][1], k1, z, 0, 0, 0);
      sc[t] = z;
    }
#pragma unroll
    for (int t = 0; t < 5; ++t) {
      const bool valid = ((t << 4) + l15) < TXT_;
#pragma unroll
      for (int r = 0; r < 4; ++r)
        sc[t][r] = valid ? sc[t][r] * scale : -1e30f;
    }

#pragma unroll
    for (int r = 0; r < 4; ++r) {
      float m = sc[0][r];
#pragma unroll
      for (int t = 1; t < 5; ++t) m = fmaxf(m, sc[t][r]);
      m = fmaxf(m, __shfl_xor(m, 1));
      m = fmaxf(m, __shfl_xor(m, 2));
      m = fmaxf(m, __shfl_xor(m, 4));
      m = fmaxf(m, __shfl_xor(m, 8));
      float l = 0.f;
#pragma unroll
      for (int t = 0; t < 5; ++t) { const float p = __expf(sc[t][r] - m); sc[t][r] = p; l += p; }
      l += __shfl_xor(l, 1);
      l += __shfl_xor(l, 2);
      l += __shfl_xor(l, 4);
      l += __shfl_xor(l, 8);
      const float inv = 1.f / l;
      const int row = prow0 + r;
#pragma unroll
      for (int t = 0; t < 5; ++t)
        *(bf16_t*)(pw + row * 256 + ((((t << 4) + l15) * 2) ^ ((row & 7) << 4))) =
            (bf16_t)(sc[t][r] * inv);
    }

    {
      const bf16x8 ki0 = ld16((char*)Kip_lds + l15 * 128 + ((hi ^ (l15 & 7)) << 4));
      const bf16x8 ki1 = ld16((char*)Kip_lds + l15 * 128 + (((4 + hi) ^ (l15 & 7)) << 4));
      f32x4 z = {0.f, 0.f, 0.f, 0.f};
      z = __builtin_amdgcn_mfma_f32_16x16x32_bf16(qf[ms][0], ki0, z, 0, 0, 0);
      z = __builtin_amdgcn_mfma_f32_16x16x32_bf16(qf[ms][1], ki1, z, 0, 0, 0);
      const bool vip = l15 < 4;
#pragma unroll
      for (int r = 0; r < 4; ++r) {
        const float s = vip ? z[r] * scale : -1e30f;
        float m = s;
        m = fmaxf(m, __shfl_xor(m, 1));
        m = fmaxf(m, __shfl_xor(m, 2));
        m = fmaxf(m, __shfl_xor(m, 4));
        m = fmaxf(m, __shfl_xor(m, 8));
        const float p = __expf(s - m);
        float l = p;
        l += __shfl_xor(l, 1);
        l += __shfl_xor(l, 2);
        l += __shfl_xor(l, 4);
        l += __shfl_xor(l, 8);
        const int row = prow0 + r;
        *(bf16_t*)(pw + row * 256 + (((96 + l15) * 2) ^ ((row & 7) << 4))) =
            (bf16_t)(p * (1.f / l));
      }
    }

    f32x4 o[4] = {};
#pragma unroll
    for (int s = 0; s < 4; ++s) {
      const bf16x8 pa =
          ld16(pw + l15 * 256 + ((((s << 2) + hi) << 4) ^ ((l15 & 7) << 4)));
#pragma unroll
      for (int n = 0; n < 4; ++n) {
        const int d = (n << 4) + l15;
        const bf16x8 vb =
            ld16((char*)Vt_lds + d * 256 + ((((s << 2) + hi) << 4) ^ ((d & 7) << 4)));
        o[n] = __builtin_amdgcn_mfma_f32_16x16x32_bf16(pa, vb, o[n], 0, 0, 0);
      }
    }

    const long orow = qrow0 + ms * 16 + prow0;
#pragma unroll
    for (int n = 0; n < 4; ++n)
#pragma unroll
      for (int r = 0; r < 4; ++r)
        outp[(orow + r) * 1280 + kvcol + (n << 4) + l15] = (bf16_t)o[n][r];
  }
}

// ---------------------------------------------------------------------------
// Utility kernels
// ---------------------------------------------------------------------------
__global__ void cvt_bf16(const float* __restrict__ in, bf16_t* __restrict__ out, long n)
{
  const long i = ((long)blockIdx.x * 256 + threadIdx.x) * 4;
  if (i >= n) return;
  const float4 v = *(const float4*)(in + i);
  bf16x4 r;
  r[0] = (bf16_t)v.x; r[1] = (bf16_t)v.y; r[2] = (bf16_t)v.z; r[3] = (bf16_t)v.w;
  *(bf16x4*)(out + i) = r;
}

// merged weight transpose+cvt: z selects which weight; in K x 1280 fp32 ->
// out 1280 x K bf16 (row stride = K). Grid (64, 40, 6); z<2 has K=1280.
__global__ void transpose_all(const float* __restrict__ Wq, const float* __restrict__ Wo,
                              const float* __restrict__ Wk, const float* __restrict__ Wv,
                              const float* __restrict__ Wki, const float* __restrict__ Wvi,
                              bf16_t* __restrict__ Wq_t, bf16_t* __restrict__ Wo_t,
                              bf16_t* __restrict__ Wkv_t, bf16_t* __restrict__ Wip_t)
{
  const int z = blockIdx.z;
  const float* in;
  bf16_t* out;
  int K;
  switch (z) {
    case 0:  in = Wq;  out = Wq_t;                        K = 1280; break;
    case 1:  in = Wo;  out = Wo_t;                        K = 1280; break;
    case 2:  in = Wk;  out = Wkv_t;                       K = 2048; break;
    case 3:  in = Wv;  out = Wkv_t + (long)1280 * 2048;   K = 2048; break;
    case 4:  in = Wki; out = Wip_t;                       K = 2048; break;
    default: in = Wvi; out = Wip_t + (long)1280 * 2048;   K = 2048; break;
  }
  const int k0 = blockIdx.x * 32, n0 = blockIdx.y * 32;
  if (k0 >= K) return;
  __shared__ float tile[32][33];
  for (int i = threadIdx.y; i < 32; i += 8)
    tile[i][threadIdx.x] = in[(long)(k0 + i) * 1280 + n0 + threadIdx.x];
  __syncthreads();
  for (int i = threadIdx.y; i < 32; i += 8)
    out[(long)(n0 + i) * K + k0 + threadIdx.x] = (bf16_t)tile[threadIdx.x][i];
}

__global__ void pack_enc(const float* __restrict__ enc, bf16_t* __restrict__ a_txt,
                         bf16_t* __restrict__ a_ip)
{
  const long t4 = ((long)blockIdx.x * 256 + threadIdx.x) * 4;
  const long NTXT = 640L * 2048;
  bf16x4 r;
  r[0] = r[1] = r[2] = r[3] = (bf16_t)0.f;
  if (t4 < NTXT) {
    const int row = (int)(t4 >> 11), col = (int)(t4 & 2047);
    const int b = row / 80, j = row - b * 80;
    if (j < TXT_) {
      const float4 v = *(const float4*)(enc + (((long)(b * 81 + j)) << 11) + col);
      r[0] = (bf16_t)v.x; r[1] = (bf16_t)v.y; r[2] = (bf16_t)v.z; r[3] = (bf16_t)v.w;
    }
    *(bf16x4*)(a_txt + t4) = r;
  } else {
    const long u = t4 - NTXT;
    const int row = (int)(u >> 11), col = (int)(u & 2047);
    if (row < 32) {
      const int b = row >> 2, j = row & 3;
      const float4 v = *(const float4*)(enc + (((long)(b * 81 + TXT_ + j)) << 11) + col);
      r[0] = (bf16_t)v.x; r[1] = (bf16_t)v.y; r[2] = (bf16_t)v.z; r[3] = (bf16_t)v.w;
    }
    *(bf16x4*)(a_ip + u) = r;
  }
}

// ---------------------------------------------------------------------------
extern "C" void kernel_launch(void* const* d_in, const int* in_sizes, int n_in,
                              void* d_out, int out_size, void* d_ws, size_t ws_size,
                              hipStream_t stream)
{
  (void)in_sizes; (void)n_in; (void)out_size; (void)ws_size;
  const float* hs  = (const float*)d_in[0];
  const float* enc = (const float*)d_in[1];
  const float* Wq  = (const float*)d_in[2];
  const float* Wk  = (const float*)d_in[3];
  const float* Wv  = (const float*)d_in[4];
  const float* Wki = (const float*)d_in[5];
  const float* Wvi = (const float*)d_in[6];
  const float* Wo  = (const float*)d_in[7];
  const float* bo  = (const float*)d_in[8];

  char* ws = (char*)d_ws;
  size_t off = 0;
  auto alloc = [&](size_t bytes) {
    char* p = ws + off;
    off += (bytes + 255) & ~(size_t)255;
    return p;
  };
  bf16_t* buf1   = (bf16_t*)alloc(83886080);  // hs_bf16 (A of GEMM1 + residual of GEMM2)
  bf16_t* qb     = (bf16_t*)alloc(83886080);  // Q (32768 x 1280), attn in-place
  bf16_t* Wq_t   = (bf16_t*)alloc(3276800);
  bf16_t* Wo_t   = (bf16_t*)alloc(3276800);
  bf16_t* Wkv_t  = (bf16_t*)alloc(10485760);
  bf16_t* Wip_t  = (bf16_t*)alloc(10485760);
  bf16_t* a_txt  = (bf16_t*)alloc(2621440);
  bf16_t* a_ip   = (bf16_t*)alloc(524288);
  bf16_t* kv_txt = (bf16_t*)alloc(3276800);
  bf16_t* kv_ip  = (bf16_t*)alloc(655360);

  cvt_bf16<<<40960, 256, 0, stream>>>(hs, buf1, 41943040L);
  transpose_all<<<dim3(64, 40, 6), dim3(32, 8), 0, stream>>>(
      Wq, Wo, Wk, Wv, Wki, Wvi, Wq_t, Wo_t, Wkv_t, Wip_t);
  pack_enc<<<1536, 256, 0, stream>>>(enc, a_txt, a_ip);

  // Q = hs_bf16 @ Wq   (256^2 dbuf-2, 2 blocks/CU, XCD-chunked swizzle)
  gemm256<0><<<640, 512, 0, stream>>>(buf1, Wq_t, qb, 5, 1280, 1280,
                                      nullptr, nullptr);
  // K|V and Kip|Vip projections in one dispatch
  gemm_small<<<120, 256, 0, stream>>>(a_txt, Wkv_t, kv_txt, a_ip, Wip_t, kv_ip);

  // fused dual-softmax attention, in-place on qb
  attn_fused<<<dim3(16, 20, 8), 256, 0, stream>>>(qb, kv_txt, kv_ip, qb);

  // out = attn @ Wo + bo + residual(bf16)
  gemm256<2><<<640, 512, 0, stream>>>(qb, Wo_t, d_out, 5, 1280, 1280,
                                      bo, buf1);
}

// Round 10
// 480.559 us; speedup vs baseline: 4.1110x; 4.1110x over previous
//
#include <hip/hip_runtime.h>
#include <hip/hip_bf16.h>
#include <cstdint>
#include <cstddef>

// ---------------------------------------------------------------------------
// IPAttnProcessor: out = (softmax(QK^T)V + softmax(QKip^T)Vip) @ Wo + bo + residual
// B=8 SQ=4096 C=1280 CAD=2048 H=20 D=64 TXT=77 NT=4 IP_SCALE=1
// Big GEMMs: 256^2 tile, BK=32, 64KB dbuf-2 LDS -> 2 blocks/CU.
// __launch_bounds__(512,2): r9's (512,4) capped VGPR at 128 -> acc spilled to
// scratch (FETCH 126MB->1.1GB, 6x slower). (512,2) keeps ~104 VGPR, no spill,
// and 64KB LDS still gives 2 blocks/CU (16 waves/CU).
// LDS-packed bf16 epilogue. Merged utility launches.
// ---------------------------------------------------------------------------

typedef __bf16 bf16_t;
typedef __bf16 bf16x8 __attribute__((ext_vector_type(8)));
typedef __bf16 bf16x4 __attribute__((ext_vector_type(4)));
typedef float  f32x4  __attribute__((ext_vector_type(4)));
typedef unsigned int u32x4 __attribute__((ext_vector_type(4)));

using as3_void  = __attribute__((address_space(3))) void;
using as1_cvoid = const __attribute__((address_space(1))) void;

#define TXT_ 77

__device__ __forceinline__ bf16x8 ld16(const void* p) {
  u32x4 v = *(const u32x4*)p;
  return __builtin_bit_cast(bf16x8, v);
}

// ---------------------------------------------------------------------------
// Big GEMM: C[M,N] = A[M,K] @ Bt[N,K]^T. 256x256 tile, BK=32, 512 thr (8 waves
// = 2M x 4N, per-wave 128x64, acc[8][4]). LDS 64KB: 2 bufs x (A 16KB + B 16KB)
// -> 2 blocks/CU at <=128 VGPR. m97 loop: __syncthreads (drains vmcnt) then
// stage(t+1) into buf^1; frags + 32 MFMA from buf. Staging/read swizzle
// byte-identical to r4 (verified 0 bank conflicts).
// EPI=0: LDS-packed bf16 epilogue, two 128-row passes (full-line 512B stores).
// EPI=2: f32 + bias[col] + bf16 residual (64B stores, no amp).
// ---------------------------------------------------------------------------
template <int EPI>
__global__ __launch_bounds__(512, 2)
void gemm256(const bf16_t* __restrict__ A, const bf16_t* __restrict__ Bt,
             void* __restrict__ Cout, int ntn, int N, int K,
             const float* __restrict__ bias, const void* __restrict__ residual)
{
  __shared__ __align__(16) char smem[2][32768]; // per buf: A @0 16KB, B @16KB
  const int tid = threadIdx.x, lane = tid & 63, wid = tid >> 6;
  const int wm = wid >> 2, wn = wid & 3;

  const int nwg = gridDim.x;
  int g = blockIdx.x;
  if ((nwg & 7) == 0) g = (blockIdx.x & 7) * (nwg >> 3) + (blockIdx.x >> 3);
  const long bm = (long)(g / ntn) * 256;
  const long bn = (long)(g % ntn) * 256;
  const int NTk = K >> 5;

  // staging: 1KB unit = 16 rows x 64B; lane -> row (lane>>2), phys chunk lane&3
  // holding logical chunk (lane&3)^((lane>>3)&3)  [r4-verified, 0 conflicts]
  const int srow = lane >> 2;
  const int scol = ((lane & 3) ^ ((lane >> 3) & 3)) * 8;

  auto stage = [&](int buf, int t) {
    const long k0 = (long)t << 5;
#pragma unroll
    for (int j = 0; j < 2; ++j) {
      const int ci = j * 8 + wid;
      const bf16_t* ga = A + (bm + ci * 16 + srow) * (long)K + k0 + scol;
      __builtin_amdgcn_global_load_lds((as1_cvoid*)ga,
          (as3_void*)(&smem[buf][ci * 1024]), 16, 0, 0);
      const bf16_t* gb = Bt + (bn + ci * 16 + srow) * (long)K + k0 + scol;
      __builtin_amdgcn_global_load_lds((as1_cvoid*)gb,
          (as3_void*)(&smem[buf][16384 + ci * 1024]), 16, 0, 0);
    }
  };

  const int l15 = lane & 15, kq = lane >> 4;
  const int rc16 = (kq ^ ((l15 >> 1) & 3)) << 4; // read-side swizzled 16B chunk

  f32x4 acc[8][4] = {};
  bf16x8 afr[4], bfr[4];

  stage(0, 0);
  int cur = 0;
  for (int t = 0; t < NTk; ++t) {
    __syncthreads(); // compiler emits vmcnt(0)+lgkmcnt(0) drain: buf[cur] ready
    if (t + 1 < NTk) stage(cur ^ 1, t + 1);
    const char* sa = smem[cur];
    const char* sb = smem[cur] + 16384;
#pragma unroll
    for (int n = 0; n < 4; ++n)
      bfr[n] = ld16(sb + (wn * 64 + n * 16 + l15) * 64 + rc16);
#pragma unroll
    for (int m = 0; m < 4; ++m)
      afr[m] = ld16(sa + (wm * 128 + m * 16 + l15) * 64 + rc16);
#pragma unroll
    for (int m = 0; m < 4; ++m)
#pragma unroll
      for (int n = 0; n < 4; ++n)
        acc[m][n] = __builtin_amdgcn_mfma_f32_16x16x32_bf16(afr[m], bfr[n], acc[m][n], 0, 0, 0);
#pragma unroll
    for (int m = 0; m < 4; ++m)
      afr[m] = ld16(sa + (wm * 128 + (m + 4) * 16 + l15) * 64 + rc16);
#pragma unroll
    for (int m = 0; m < 4; ++m)
#pragma unroll
      for (int n = 0; n < 4; ++n)
        acc[m + 4][n] = __builtin_amdgcn_mfma_f32_16x16x32_bf16(afr[m], bfr[n], acc[m + 4][n], 0, 0, 0);
    cur ^= 1;
  }

  const int orow0 = (lane >> 4) << 2;
  if constexpr (EPI == 0) {
    // LDS-packed epilogue in two 128-row passes (64KB = [128][256] bf16).
    bf16_t* cl = (bf16_t*)smem;
    const int rr = tid >> 5, cc = tid & 31;
#pragma unroll
    for (int h = 0; h < 2; ++h) {
      __syncthreads();
      if (wm == h) {
#pragma unroll
        for (int m = 0; m < 8; ++m)
#pragma unroll
          for (int n = 0; n < 4; ++n)
#pragma unroll
            for (int r = 0; r < 4; ++r)
              cl[(m * 16 + orow0 + r) * 256 + wn * 64 + n * 16 + l15] =
                  (bf16_t)acc[m][n][r];
      }
      __syncthreads();
#pragma unroll
      for (int s = 0; s < 8; ++s) {
        const int row = s * 16 + rr;
        const u32x4 v = *(const u32x4*)(cl + row * 256 + cc * 8);
        *(u32x4*)((bf16_t*)Cout + (bm + h * 128 + row) * (long)N + bn + cc * 8) = v;
      }
    }
  } else {
#pragma unroll
    for (int m = 0; m < 8; ++m) {
#pragma unroll
      for (int n = 0; n < 4; ++n) {
        const long col = bn + wn * 64 + n * 16 + l15;
#pragma unroll
        for (int r = 0; r < 4; ++r) {
          const long row = bm + wm * 128 + m * 16 + orow0 + r;
          ((float*)Cout)[row * N + col] =
              acc[m][n][r] + bias[col] +
              (float)((const bf16_t*)residual)[row * N + col];
        }
      }
    }
  }
}

// ---------------------------------------------------------------------------
// Merged small GEMM (m97 128^2 structure): blocks 0-99 -> K|V proj (M=640),
// blocks 100-119 -> Kip|Vip proj (M=128). N=2560, K=2048, ntn=20 for both.
// ---------------------------------------------------------------------------
__global__ __launch_bounds__(256, 4)
void gemm_small(const bf16_t* __restrict__ A0, const bf16_t* __restrict__ B0,
                bf16_t* __restrict__ C0,
                const bf16_t* __restrict__ A1, const bf16_t* __restrict__ B1,
                bf16_t* __restrict__ C1)
{
  __shared__ __align__(16) char smem[2][16384];
  const int tid  = threadIdx.x;
  const int lane = tid & 63;
  const int wid  = tid >> 6;
  const int wm = wid >> 1, wn = wid & 1;

  const bf16_t *A, *Bt;
  bf16_t* Cout;
  int g = blockIdx.x;
  if (g < 100) { A = A0; Bt = B0; Cout = C0; }
  else         { A = A1; Bt = B1; Cout = C1; g -= 100; }
  const int ntn = 20, N = 2560, K = 2048;

  const long bm = (long)(g / ntn) * 128;
  const long bn = (long)(g % ntn) * 128;

  f32x4 acc[4][4] = {};

  const int srow = lane >> 2;
  const int skb  = (lane & 3) ^ (((lane >> 2) ^ (lane >> 4)) & 3);
  const int NT = K >> 5;

  auto stage = [&](int buf, int kt) {
    const int k0 = kt << 5;
#pragma unroll
    for (int cc = 0; cc < 2; ++cc) {
      const int c = wid + cc * 4;
      const bf16_t* ga = A + (bm + c * 16 + srow) * (long)K + (k0 + skb * 8);
      __builtin_amdgcn_global_load_lds((as1_cvoid*)ga,
                                       (as3_void*)(&smem[buf][c * 1024]), 16, 0, 0);
      const bf16_t* gb = Bt + (bn + c * 16 + srow) * (long)K + (k0 + skb * 8);
      __builtin_amdgcn_global_load_lds((as1_cvoid*)gb,
                                       (as3_void*)(&smem[buf][8192 + c * 1024]), 16, 0, 0);
    }
  };

  const int rkb    = (((lane >> 4) ^ (lane & 3) ^ ((lane >> 2) & 3)) & 3) << 4;
  const int rrow_a = wm * 64 + (lane & 15);
  const int rrow_b = wn * 64 + (lane & 15);

  stage(0, 0);
  int cur = 0;
  for (int t = 0; t < NT; ++t) {
    __syncthreads();
    if (t + 1 < NT) stage(cur ^ 1, t + 1);
    const char* sa = smem[cur];
    const char* sb = smem[cur] + 8192;
    bf16x8 af[4], bfv[4];
#pragma unroll
    for (int m = 0; m < 4; ++m)
      af[m] = ld16(sa + (rrow_a + m * 16) * 64 + rkb);
#pragma unroll
    for (int n = 0; n < 4; ++n)
      bfv[n] = ld16(sb + (rrow_b + n * 16) * 64 + rkb);
#pragma unroll
    for (int m = 0; m < 4; ++m)
#pragma unroll
      for (int n = 0; n < 4; ++n)
        acc[m][n] = __builtin_amdgcn_mfma_f32_16x16x32_bf16(af[m], bfv[n], acc[m][n], 0, 0, 0);
    cur ^= 1;
  }

  const int orow0 = wm * 64 + ((lane >> 4) << 2);
  const int ocol0 = wn * 64 + (lane & 15);
#pragma unroll
  for (int m = 0; m < 4; ++m)
#pragma unroll
    for (int n = 0; n < 4; ++n) {
      const long col = bn + ocol0 + n * 16;
#pragma unroll
      for (int r = 0; r < 4; ++r)
        Cout[(bm + orow0 + m * 16 + r) * (long)N + col] = (bf16_t)acc[m][n][r];
    }
}

// ---------------------------------------------------------------------------
// Fused attention (unchanged; writes in-place over Q).
// ---------------------------------------------------------------------------
__global__ __launch_bounds__(256, 3)
void attn_fused(const bf16_t* __restrict__ q, const bf16_t* __restrict__ kvt,
                const bf16_t* __restrict__ kvip, bf16_t* __restrict__ outp)
{
  __shared__ __align__(16) bf16_t K_lds[80 * 64];
  __shared__ __align__(16) bf16_t Kip_lds[16 * 64];
  __shared__ __align__(16) bf16_t Vt_lds[64 * 128];
  __shared__ __align__(16) bf16_t P_lds[4][16 * 128];

  const int tid = threadIdx.x, lane = tid & 63, wid = tid >> 6;
  const int h = blockIdx.y, b = blockIdx.z;
  const int kvcol = h << 6;

  for (int idx = tid; idx < 640; idx += 256) {
    const int j = idx >> 3, c = idx & 7;
    bf16x8 v = {};
    if (j < TXT_) v = ld16(kvt + (long)(b * 80 + j) * 2560 + kvcol + c * 8);
    *(bf16x8*)((char*)K_lds + j * 128 + ((c ^ (j & 7)) << 4)) = v;
  }
  if (tid < 128) {
    const int j = tid >> 3, c = tid & 7;
    bf16x8 v = {};
    if (j < 4) v = ld16(kvip + (long)(b * 4 + j) * 2560 + kvcol + c * 8);
    *(bf16x8*)((char*)Kip_lds + j * 128 + ((c ^ (j & 7)) << 4)) = v;
  }
  for (int idx = tid; idx < 1024; idx += 256) {
    const int key = idx >> 3, c = idx & 7;
    bf16x8 v = {};
    if (key < TXT_)
      v = ld16(kvt + (long)(b * 80 + key) * 2560 + 1280 + kvcol + c * 8);
    else if (key >= 96 && key < 100)
      v = ld16(kvip + (long)(b * 4 + key - 96) * 2560 + 1280 + kvcol + c * 8);
#pragma unroll
    for (int e = 0; e < 8; ++e) {
      const int d = c * 8 + e;
      *(bf16_t*)((char*)Vt_lds + d * 256 + ((key * 2) ^ ((d & 7) << 4))) = v[e];
    }
  }
  for (int idx = tid; idx < 1024; idx += 256)
    *(bf16x8*)((char*)P_lds + idx * 16) = (bf16x8){};
  __syncthreads();

  const int l15 = lane & 15, hi = lane >> 4;
  const int dblk = hi << 3;
  const int prow0 = hi << 2;
  const float scale = 0.125f;
  char* const pw = (char*)P_lds[wid];

  const long qrow0 = (long)b * 4096 + ((long)blockIdx.x << 8) + (wid << 6);
  bf16x8 qf[4][2];
#pragma unroll
  for (int ms = 0; ms < 4; ++ms) {
    const bf16_t* qp = q + (qrow0 + ms * 16 + l15) * 1280 + kvcol;
    qf[ms][0] = ld16(qp + dblk);
    qf[ms][1] = ld16(qp + 32 + dblk);
  }

#pragma unroll
  for (int ms = 0; ms < 4; ++ms) {
    f32x4 sc[5];
#pragma unroll
    for (int t = 0; t < 5; ++t) {
      const int j = (t << 4) + l15;
      const bf16x8 k0 = ld16((char*)K_lds + j * 128 + ((hi ^ (j & 7)) << 4));
      const bf16x8 k1 = ld16((char*)K_lds + j * 128 + (((4 + hi) ^ (j & 7)) << 4));
      f32x4 z = {0.f, 0.f, 0.f, 0.f};
      z = __builtin_amdgcn_mfma_f32_16x16x32_bf16(qf[ms][0], k0, z, 0, 0, 0);
      z = __builtin_amdgcn_mfma_f32_16x16x32_bf16(qf[ms][1], k1, z, 0, 0, 0);
      sc[t] = z;
    }
#pragma unroll
    for (int t = 0; t < 5; ++t) {
      const bool valid = ((t << 4) + l15) < TXT_;
#pragma unroll
      for (int r = 0; r < 4; ++r)
        sc[t][r] = valid ? sc[t][r] * scale : -1e30f;
    }

#pragma unroll
    for (int r = 0; r < 4; ++r) {
      float m = sc[0][r];
#pragma unroll
      for (int t = 1; t < 5; ++t) m = fmaxf(m, sc[t][r]);
      m = fmaxf(m, __shfl_xor(m, 1));
      m = fmaxf(m, __shfl_xor(m, 2));
      m = fmaxf(m, __shfl_xor(m, 4));
      m = fmaxf(m, __shfl_xor(m, 8));
      float l = 0.f;
#pragma unroll
      for (int t = 0; t < 5; ++t) { const float p = __expf(sc[t][r] - m); sc[t][r] = p; l += p; }
      l += __shfl_xor(l, 1);
      l += __shfl_xor(l, 2);
      l += __shfl_xor(l, 4);
      l += __shfl_xor(l, 8);
      const float inv = 1.f / l;
      const int row = prow0 + r;
#pragma unroll
      for (int t = 0; t < 5; ++t)
        *(bf16_t*)(pw + row * 256 + ((((t << 4) + l15) * 2) ^ ((row & 7) << 4))) =
            (bf16_t)(sc[t][r] * inv);
    }

    {
      const bf16x8 ki0 = ld16((char*)Kip_lds + l15 * 128 + ((hi ^ (l15 & 7)) << 4));
      const bf16x8 ki1 = ld16((char*)Kip_lds + l15 * 128 + (((4 + hi) ^ (l15 & 7)) << 4));
      f32x4 z = {0.f, 0.f, 0.f, 0.f};
      z = __builtin_amdgcn_mfma_f32_16x16x32_bf16(qf[ms][0], ki0, z, 0, 0, 0);
      z = __builtin_amdgcn_mfma_f32_16x16x32_bf16(qf[ms][1], ki1, z, 0, 0, 0);
      const bool vip = l15 < 4;
#pragma unroll
      for (int r = 0; r < 4; ++r) {
        const float s = vip ? z[r] * scale : -1e30f;
        float m = s;
        m = fmaxf(m, __shfl_xor(m, 1));
        m = fmaxf(m, __shfl_xor(m, 2));
        m = fmaxf(m, __shfl_xor(m, 4));
        m = fmaxf(m, __shfl_xor(m, 8));
        const float p = __expf(s - m);
        float l = p;
        l += __shfl_xor(l, 1);
        l += __shfl_xor(l, 2);
        l += __shfl_xor(l, 4);
        l += __shfl_xor(l, 8);
        const int row = prow0 + r;
        *(bf16_t*)(pw + row * 256 + (((96 + l15) * 2) ^ ((row & 7) << 4))) =
            (bf16_t)(p * (1.f / l));
      }
    }

    f32x4 o[4] = {};
#pragma unroll
    for (int s = 0; s < 4; ++s) {
      const bf16x8 pa =
          ld16(pw + l15 * 256 + ((((s << 2) + hi) << 4) ^ ((l15 & 7) << 4)));
#pragma unroll
      for (int n = 0; n < 4; ++n) {
        const int d = (n << 4) + l15;
        const bf16x8 vb =
            ld16((char*)Vt_lds + d * 256 + ((((s << 2) + hi) << 4) ^ ((d & 7) << 4)));
        o[n] = __builtin_amdgcn_mfma_f32_16x16x32_bf16(pa, vb, o[n], 0, 0, 0);
      }
    }

    const long orow = qrow0 + ms * 16 + prow0;
#pragma unroll
    for (int n = 0; n < 4; ++n)
#pragma unroll
      for (int r = 0; r < 4; ++r)
        outp[(orow + r) * 1280 + kvcol + (n << 4) + l15] = (bf16_t)o[n][r];
  }
}

// ---------------------------------------------------------------------------
// Utility kernels
// ---------------------------------------------------------------------------
__global__ void cvt_bf16(const float* __restrict__ in, bf16_t* __restrict__ out, long n)
{
  const long i = ((long)blockIdx.x * 256 + threadIdx.x) * 4;
  if (i >= n) return;
  const float4 v = *(const float4*)(in + i);
  bf16x4 r;
  r[0] = (bf16_t)v.x; r[1] = (bf16_t)v.y; r[2] = (bf16_t)v.z; r[3] = (bf16_t)v.w;
  *(bf16x4*)(out + i) = r;
}

// merged weight transpose+cvt: z selects which weight; in K x 1280 fp32 ->
// out 1280 x K bf16 (row stride = K). Grid (64, 40, 6); z<2 has K=1280.
__global__ void transpose_all(const float* __restrict__ Wq, const float* __restrict__ Wo,
                              const float* __restrict__ Wk, const float* __restrict__ Wv,
                              const float* __restrict__ Wki, const float* __restrict__ Wvi,
                              bf16_t* __restrict__ Wq_t, bf16_t* __restrict__ Wo_t,
                              bf16_t* __restrict__ Wkv_t, bf16_t* __restrict__ Wip_t)
{
  const int z = blockIdx.z;
  const float* in;
  bf16_t* out;
  int K;
  switch (z) {
    case 0:  in = Wq;  out = Wq_t;                        K = 1280; break;
    case 1:  in = Wo;  out = Wo_t;                        K = 1280; break;
    case 2:  in = Wk;  out = Wkv_t;                       K = 2048; break;
    case 3:  in = Wv;  out = Wkv_t + (long)1280 * 2048;   K = 2048; break;
    case 4:  in = Wki; out = Wip_t;                       K = 2048; break;
    default: in = Wvi; out = Wip_t + (long)1280 * 2048;   K = 2048; break;
  }
  const int k0 = blockIdx.x * 32, n0 = blockIdx.y * 32;
  if (k0 >= K) return;
  __shared__ float tile[32][33];
  for (int i = threadIdx.y; i < 32; i += 8)
    tile[i][threadIdx.x] = in[(long)(k0 + i) * 1280 + n0 + threadIdx.x];
  __syncthreads();
  for (int i = threadIdx.y; i < 32; i += 8)
    out[(long)(n0 + i) * K + k0 + threadIdx.x] = (bf16_t)tile[threadIdx.x][i];
}

__global__ void pack_enc(const float* __restrict__ enc, bf16_t* __restrict__ a_txt,
                         bf16_t* __restrict__ a_ip)
{
  const long t4 = ((long)blockIdx.x * 256 + threadIdx.x) * 4;
  const long NTXT = 640L * 2048;
  bf16x4 r;
  r[0] = r[1] = r[2] = r[3] = (bf16_t)0.f;
  if (t4 < NTXT) {
    const int row = (int)(t4 >> 11), col = (int)(t4 & 2047);
    const int b = row / 80, j = row - b * 80;
    if (j < TXT_) {
      const float4 v = *(const float4*)(enc + (((long)(b * 81 + j)) << 11) + col);
      r[0] = (bf16_t)v.x; r[1] = (bf16_t)v.y; r[2] = (bf16_t)v.z; r[3] = (bf16_t)v.w;
    }
    *(bf16x4*)(a_txt + t4) = r;
  } else {
    const long u = t4 - NTXT;
    const int row = (int)(u >> 11), col = (int)(u & 2047);
    if (row < 32) {
      const int b = row >> 2, j = row & 3;
      const float4 v = *(const float4*)(enc + (((long)(b * 81 + TXT_ + j)) << 11) + col);
      r[0] = (bf16_t)v.x; r[1] = (bf16_t)v.y; r[2] = (bf16_t)v.z; r[3] = (bf16_t)v.w;
    }
    *(bf16x4*)(a_ip + u) = r;
  }
}

// ---------------------------------------------------------------------------
extern "C" void kernel_launch(void* const* d_in, const int* in_sizes, int n_in,
                              void* d_out, int out_size, void* d_ws, size_t ws_size,
                              hipStream_t stream)
{
  (void)in_sizes; (void)n_in; (void)out_size; (void)ws_size;
  const float* hs  = (const float*)d_in[0];
  const float* enc = (const float*)d_in[1];
  const float* Wq  = (const float*)d_in[2];
  const float* Wk  = (const float*)d_in[3];
  const float* Wv  = (const float*)d_in[4];
  const float* Wki = (const float*)d_in[5];
  const float* Wvi = (const float*)d_in[6];
  const float* Wo  = (const float*)d_in[7];
  const float* bo  = (const float*)d_in[8];

  char* ws = (char*)d_ws;
  size_t off = 0;
  auto alloc = [&](size_t bytes) {
    char* p = ws + off;
    off += (bytes + 255) & ~(size_t)255;
    return p;
  };
  bf16_t* buf1   = (bf16_t*)alloc(83886080);  // hs_bf16 (A of GEMM1 + residual of GEMM2)
  bf16_t* qb     = (bf16_t*)alloc(83886080);  // Q (32768 x 1280), attn in-place
  bf16_t* Wq_t   = (bf16_t*)alloc(3276800);
  bf16_t* Wo_t   = (bf16_t*)alloc(3276800);
  bf16_t* Wkv_t  = (bf16_t*)alloc(10485760);
  bf16_t* Wip_t  = (bf16_t*)alloc(10485760);
  bf16_t* a_txt  = (bf16_t*)alloc(2621440);
  bf16_t* a_ip   = (bf16_t*)alloc(524288);
  bf16_t* kv_txt = (bf16_t*)alloc(3276800);
  bf16_t* kv_ip  = (bf16_t*)alloc(655360);

  cvt_bf16<<<40960, 256, 0, stream>>>(hs, buf1, 41943040L);
  transpose_all<<<dim3(64, 40, 6), dim3(32, 8), 0, stream>>>(
      Wq, Wo, Wk, Wv, Wki, Wvi, Wq_t, Wo_t, Wkv_t, Wip_t);
  pack_enc<<<1536, 256, 0, stream>>>(enc, a_txt, a_ip);

  // Q = hs_bf16 @ Wq   (256^2 dbuf-2, 2 blocks/CU, XCD-chunked swizzle)
  gemm256<0><<<640, 512, 0, stream>>>(buf1, Wq_t, qb, 5, 1280, 1280,
                                      nullptr, nullptr);
  // K|V and Kip|Vip projections in one dispatch
  gemm_small<<<120, 256, 0, stream>>>(a_txt, Wkv_t, kv_txt, a_ip, Wip_t, kv_ip);

  // fused dual-softmax attention, in-place on qb
  attn_fused<<<dim3(16, 20, 8), 256, 0, stream>>>(qb, kv_txt, kv_ip, qb);

  // out = attn @ Wo + bo + residual(bf16)
  gemm256<2><<<640, 512, 0, stream>>>(qb, Wo_t, d_out, 5, 1280, 1280,
                                      bo, buf1);
}

// Round 11
// 470.702 us; speedup vs baseline: 4.1970x; 1.0209x over previous
//
#include <hip/hip_runtime.h>
#include <hip/hip_bf16.h>
#include <cstdint>
#include <cstddef>

// ---------------------------------------------------------------------------
// IPAttnProcessor: out = (softmax(QK^T)V + softmax(QKip^T)Vip) @ Wo + bo + residual
// B=8 SQ=4096 C=1280 CAD=2048 H=20 D=64 TXT=77 NT=4 IP_SCALE=1
// Big GEMMs: r8 config (256^2, BK=32, ring-4 LDS 128KB, counted vmcnt, 16x16
// MFMA, 0 bank conflicts, LDS-packed bf16 epilogue). GEMM1 stages A directly
// from fp32 (T14 split reg-staging; kills the separate cvt pass + 252MB).
// GEMM2 epilogue reads fp32 residual. Merged utility launches.
// ---------------------------------------------------------------------------

typedef __bf16 bf16_t;
typedef __bf16 bf16x8 __attribute__((ext_vector_type(8)));
typedef __bf16 bf16x4 __attribute__((ext_vector_type(4)));
typedef float  f32x4  __attribute__((ext_vector_type(4)));
typedef unsigned int u32x4 __attribute__((ext_vector_type(4)));

using as3_void  = __attribute__((address_space(3))) void;
using as1_cvoid = const __attribute__((address_space(1))) void;

#define TXT_ 77

__device__ __forceinline__ bf16x8 ld16(const void* p) {
  u32x4 v = *(const u32x4*)p;
  return __builtin_bit_cast(bf16x8, v);
}

// ---------------------------------------------------------------------------
// Big GEMM: C[M,N] = A[M,K] @ Bt[N,K]^T. 256x256 tile, BK=32, 512 thr (8 waves
// = 2M x 4N, per-wave 128x64, acc[8][4]). LDS 128KB: A ring4 @0, B ring4 @64KB.
// K-tile t reads buf[t&3]; tile t+2 staged ahead (race-free: last reader of
// that slot finished >=3 barriers ago). Tile-end counted wait, drain at NTk-2.
// AF32=0: A staged via global_load_lds (bf16 source), r8-verbatim.
// AF32=1: A staged from fp32: issueA(t+2) 4xfloat4 -> regs; writeA(t+1) cvt +
//   ds_write_b128 producing the same linear LDS image; B via gload_lds.
//   Tile-end vmcnt(6) retires exactly B(t+1) [queue: B(t+1)2,A(t+2)4,B(t+2)2].
// EPI=0: LDS-packed bf16 epilogue (512B-contiguous full-line stores).
// EPI=2: f32 + bias[col] + fp32 residual[row,col].
// ---------------------------------------------------------------------------
template <int EPI, int AF32>
__global__ __launch_bounds__(512, 2)
void gemm256(const void* __restrict__ Ap, const bf16_t* __restrict__ Bt,
             void* __restrict__ Cout, int ntn, int N, int K,
             const float* __restrict__ bias, const float* __restrict__ residual)
{
  __shared__ __align__(16) char smem[131072]; // A ring @0 (4x16KB), B @64KB
  const int tid = threadIdx.x, lane = tid & 63, wid = tid >> 6;
  const int wm = wid >> 2, wn = wid & 3;

  const int nwg = gridDim.x;
  int g = blockIdx.x;
  if ((nwg & 7) == 0) g = (blockIdx.x & 7) * (nwg >> 3) + (blockIdx.x >> 3);
  const long bm = (long)(g / ntn) * 256;
  const long bn = (long)(g % ntn) * 256;
  const int NTk = K >> 5;

  // staging: 1KB unit = 16 rows x 64B; lane -> row (lane>>2), element col
  // ((lane&3)^((lane>>3)&3))*8  [r4/r8-verified 0-conflict layout]
  const int srow = lane >> 2;
  const int scol = ((lane & 3) ^ ((lane >> 3) & 3)) * 8;

  auto stageA16 = [&](int t) { // bf16 A source (AF32=0)
    const int buf = t & 3;
    const long k0 = (long)t << 5;
#pragma unroll
    for (int j = 0; j < 2; ++j) {
      const int ci = j * 8 + wid;
      const bf16_t* gp = (const bf16_t*)Ap + (bm + ci * 16 + srow) * (long)K + k0 + scol;
      __builtin_amdgcn_global_load_lds((as1_cvoid*)gp,
          (as3_void*)(smem + buf * 16384 + ci * 1024), 16, 0, 0);
    }
  };
  auto stageB = [&](int t) {
    const int buf = t & 3;
    const long k0 = (long)t << 5;
#pragma unroll
    for (int j = 0; j < 2; ++j) {
      const int ci = j * 8 + wid;
      const bf16_t* gp = Bt + (bn + ci * 16 + srow) * (long)K + k0 + scol;
      __builtin_amdgcn_global_load_lds((as1_cvoid*)gp,
          (as3_void*)(smem + 65536 + buf * 16384 + ci * 1024), 16, 0, 0);
    }
  };

  // fp32 A reg-staging (AF32=1): persistent regs across one tile
  f32x4 aP[2][2];
  auto issueA = [&](int t) {
#pragma unroll
    for (int j = 0; j < 2; ++j) {
      const int ci = j * 8 + wid;
      const float* gp = (const float*)Ap + (bm + ci * 16 + srow) * (long)K + ((long)t << 5) + scol;
      aP[j][0] = *(const f32x4*)gp;
      aP[j][1] = *(const f32x4*)(gp + 4);
    }
  };
  auto writeA = [&](int t) { // compiler inserts the vmcnt wait on aP use
    const int buf = t & 3;
#pragma unroll
    for (int j = 0; j < 2; ++j) {
      const int ci = j * 8 + wid;
      bf16x8 v;
      v[0] = (bf16_t)aP[j][0][0]; v[1] = (bf16_t)aP[j][0][1];
      v[2] = (bf16_t)aP[j][0][2]; v[3] = (bf16_t)aP[j][0][3];
      v[4] = (bf16_t)aP[j][1][0]; v[5] = (bf16_t)aP[j][1][1];
      v[6] = (bf16_t)aP[j][1][2]; v[7] = (bf16_t)aP[j][1][3];
      *(bf16x8*)(smem + buf * 16384 + ci * 1024 + lane * 16) = v;
    }
  };

  const int l15 = lane & 15, kq = lane >> 4;
  const int rc16 = (kq ^ ((l15 >> 1) & 3)) << 4; // read-side swizzled 16B chunk

  f32x4 acc[8][4] = {};
  bf16x8 afr[4], bfr[4];

  // prologue: tiles 0,1 staged
  if constexpr (AF32) {
    issueA(0);
    writeA(0);      // waits its own loads (queue empty otherwise)
    issueA(1);      // A(1) regs held into loop iter t=0
    stageB(0); stageB(1);
    asm volatile("s_waitcnt vmcnt(2)" ::: "memory"); // retire A(1),B(0); B(1) flies
    asm volatile("s_waitcnt lgkmcnt(0)" ::: "memory");
  } else {
    stageA16(0); stageB(0); stageA16(1); stageB(1);
    asm volatile("s_waitcnt vmcnt(4)" ::: "memory"); // tile 0 resident
  }
  __builtin_amdgcn_s_barrier();

  for (int t = 0; t < NTk; ++t) {
    const char* sa = smem + (t & 3) * 16384;
    const char* sb = smem + 65536 + (t & 3) * 16384;
    const bool pf = (t + 2 < NTk);

    // ---- frags B all + A m0-3 ----
#pragma unroll
    for (int n = 0; n < 4; ++n)
      bfr[n] = ld16(sb + (wn * 64 + n * 16 + l15) * 64 + rc16);
#pragma unroll
    for (int m = 0; m < 4; ++m)
      afr[m] = ld16(sa + (wm * 128 + m * 16 + l15) * 64 + rc16);
    if constexpr (AF32) {
      if (t + 1 < NTk) writeA(t + 1);   // cvt + ds_write into buf[(t+1)&3]
      if (pf) { issueA(t + 2); stageB(t + 2); }
    } else {
      if (pf) stageA16(t + 2);
    }
    __builtin_amdgcn_s_setprio(1);
#pragma unroll
    for (int m = 0; m < 4; ++m)
#pragma unroll
      for (int n = 0; n < 4; ++n)
        acc[m][n] = __builtin_amdgcn_mfma_f32_16x16x32_bf16(afr[m], bfr[n], acc[m][n], 0, 0, 0);
    __builtin_amdgcn_s_setprio(0);

    // ---- frags A m4-7 ----
#pragma unroll
    for (int m = 0; m < 4; ++m)
      afr[m] = ld16(sa + (wm * 128 + (m + 4) * 16 + l15) * 64 + rc16);
    if constexpr (!AF32) {
      if (pf) stageB(t + 2);
    }
    __builtin_amdgcn_s_setprio(1);
#pragma unroll
    for (int m = 0; m < 4; ++m)
#pragma unroll
      for (int n = 0; n < 4; ++n)
        acc[m + 4][n] = __builtin_amdgcn_mfma_f32_16x16x32_bf16(afr[m], bfr[n], acc[m + 4][n], 0, 0, 0);
    __builtin_amdgcn_s_setprio(0);

    // ---- tile-end: counted wait (t+1 resident; t+2 in flight) ----
    __builtin_amdgcn_sched_barrier(0); // pin issue order vs the waits below
    if constexpr (AF32) {
      if (pf) asm volatile("s_waitcnt vmcnt(6)" ::: "memory"); // retire B(t+1)
      else    asm volatile("s_waitcnt vmcnt(0)" ::: "memory");
      asm volatile("s_waitcnt lgkmcnt(0)" ::: "memory");       // publish ds_writes
    } else {
      if (t == NTk - 2) asm volatile("s_waitcnt vmcnt(0)" ::: "memory");
      else              asm volatile("s_waitcnt vmcnt(4)" ::: "memory");
    }
    __builtin_amdgcn_s_barrier();
  }

  const int orow0 = (lane >> 4) << 2;
  if constexpr (EPI == 0) {
    // LDS-packed epilogue: acc -> smem bf16 [256][256] (=128KB), then full-line
    // sweeps: each row stored as 32 threads x 16B = 512B contiguous.
    bf16_t* cl = (bf16_t*)smem;
    const int lrow0 = wm * 128 + orow0;
    const int lcol0 = wn * 64 + l15;
#pragma unroll
    for (int m = 0; m < 8; ++m)
#pragma unroll
      for (int n = 0; n < 4; ++n)
#pragma unroll
        for (int r = 0; r < 4; ++r)
          cl[(lrow0 + m * 16 + r) * 256 + lcol0 + n * 16] = (bf16_t)acc[m][n][r];
    __syncthreads();
    const int rr = tid >> 5, cc = tid & 31;
#pragma unroll
    for (int s = 0; s < 16; ++s) {
      const int row = s * 16 + rr;
      const u32x4 v = *(const u32x4*)(cl + row * 256 + cc * 8);
      *(u32x4*)((bf16_t*)Cout + (bm + row) * (long)N + bn + cc * 8) = v;
    }
  } else {
#pragma unroll
    for (int m = 0; m < 8; ++m) {
#pragma unroll
      for (int n = 0; n < 4; ++n) {
        const long col = bn + wn * 64 + n * 16 + l15;
#pragma unroll
        for (int r = 0; r < 4; ++r) {
          const long row = bm + wm * 128 + m * 16 + orow0 + r;
          ((float*)Cout)[row * N + col] =
              acc[m][n][r] + bias[col] + residual[row * N + col];
        }
      }
    }
  }
}

// ---------------------------------------------------------------------------
// Merged small GEMM (m97 128^2 structure): blocks 0-99 -> K|V proj (M=640),
// blocks 100-119 -> Kip|Vip proj (M=128). N=2560, K=2048, ntn=20 for both.
// ---------------------------------------------------------------------------
__global__ __launch_bounds__(256, 4)
void gemm_small(const bf16_t* __restrict__ A0, const bf16_t* __restrict__ B0,
                bf16_t* __restrict__ C0,
                const bf16_t* __restrict__ A1, const bf16_t* __restrict__ B1,
                bf16_t* __restrict__ C1)
{
  __shared__ __align__(16) char smem[2][16384];
  const int tid  = threadIdx.x;
  const int lane = tid & 63;
  const int wid  = tid >> 6;
  const int wm = wid >> 1, wn = wid & 1;

  const bf16_t *A, *Bt;
  bf16_t* Cout;
  int g = blockIdx.x;
  if (g < 100) { A = A0; Bt = B0; Cout = C0; }
  else         { A = A1; Bt = B1; Cout = C1; g -= 100; }
  const int ntn = 20, N = 2560, K = 2048;

  const long bm = (long)(g / ntn) * 128;
  const long bn = (long)(g % ntn) * 128;

  f32x4 acc[4][4] = {};

  const int srow = lane >> 2;
  const int skb  = (lane & 3) ^ (((lane >> 2) ^ (lane >> 4)) & 3);
  const int NT = K >> 5;

  auto stage = [&](int buf, int kt) {
    const int k0 = kt << 5;
#pragma unroll
    for (int cc = 0; cc < 2; ++cc) {
      const int c = wid + cc * 4;
      const bf16_t* ga = A + (bm + c * 16 + srow) * (long)K + (k0 + skb * 8);
      __builtin_amdgcn_global_load_lds((as1_cvoid*)ga,
                                       (as3_void*)(&smem[buf][c * 1024]), 16, 0, 0);
      const bf16_t* gb = Bt + (bn + c * 16 + srow) * (long)K + (k0 + skb * 8);
      __builtin_amdgcn_global_load_lds((as1_cvoid*)gb,
                                       (as3_void*)(&smem[buf][8192 + c * 1024]), 16, 0, 0);
    }
  };

  const int rkb    = (((lane >> 4) ^ (lane & 3) ^ ((lane >> 2) & 3)) & 3) << 4;
  const int rrow_a = wm * 64 + (lane & 15);
  const int rrow_b = wn * 64 + (lane & 15);

  stage(0, 0);
  int cur = 0;
  for (int t = 0; t < NT; ++t) {
    __syncthreads();
    if (t + 1 < NT) stage(cur ^ 1, t + 1);
    const char* sa = smem[cur];
    const char* sb = smem[cur] + 8192;
    bf16x8 af[4], bfv[4];
#pragma unroll
    for (int m = 0; m < 4; ++m)
      af[m] = ld16(sa + (rrow_a + m * 16) * 64 + rkb);
#pragma unroll
    for (int n = 0; n < 4; ++n)
      bfv[n] = ld16(sb + (rrow_b + n * 16) * 64 + rkb);
#pragma unroll
    for (int m = 0; m < 4; ++m)
#pragma unroll
      for (int n = 0; n < 4; ++n)
        acc[m][n] = __builtin_amdgcn_mfma_f32_16x16x32_bf16(af[m], bfv[n], acc[m][n], 0, 0, 0);
    cur ^= 1;
  }

  const int orow0 = wm * 64 + ((lane >> 4) << 2);
  const int ocol0 = wn * 64 + (lane & 15);
#pragma unroll
  for (int m = 0; m < 4; ++m)
#pragma unroll
    for (int n = 0; n < 4; ++n) {
      const long col = bn + ocol0 + n * 16;
#pragma unroll
      for (int r = 0; r < 4; ++r)
        Cout[(bm + orow0 + m * 16 + r) * (long)N + col] = (bf16_t)acc[m][n][r];
    }
}

// ---------------------------------------------------------------------------
// Fused attention (unchanged; writes in-place over Q).
// ---------------------------------------------------------------------------
__global__ __launch_bounds__(256, 3)
void attn_fused(const bf16_t* __restrict__ q, const bf16_t* __restrict__ kvt,
                const bf16_t* __restrict__ kvip, bf16_t* __restrict__ outp)
{
  __shared__ __align__(16) bf16_t K_lds[80 * 64];
  __shared__ __align__(16) bf16_t Kip_lds[16 * 64];
  __shared__ __align__(16) bf16_t Vt_lds[64 * 128];
  __shared__ __align__(16) bf16_t P_lds[4][16 * 128];

  const int tid = threadIdx.x, lane = tid & 63, wid = tid >> 6;
  const int h = blockIdx.y, b = blockIdx.z;
  const int kvcol = h << 6;

  for (int idx = tid; idx < 640; idx += 256) {
    const int j = idx >> 3, c = idx & 7;
    bf16x8 v = {};
    if (j < TXT_) v = ld16(kvt + (long)(b * 80 + j) * 2560 + kvcol + c * 8);
    *(bf16x8*)((char*)K_lds + j * 128 + ((c ^ (j & 7)) << 4)) = v;
  }
  if (tid < 128) {
    const int j = tid >> 3, c = tid & 7;
    bf16x8 v = {};
    if (j < 4) v = ld16(kvip + (long)(b * 4 + j) * 2560 + kvcol + c * 8);
    *(bf16x8*)((char*)Kip_lds + j * 128 + ((c ^ (j & 7)) << 4)) = v;
  }
  for (int idx = tid; idx < 1024; idx += 256) {
    const int key = idx >> 3, c = idx & 7;
    bf16x8 v = {};
    if (key < TXT_)
      v = ld16(kvt + (long)(b * 80 + key) * 2560 + 1280 + kvcol + c * 8);
    else if (key >= 96 && key < 100)
      v = ld16(kvip + (long)(b * 4 + key - 96) * 2560 + 1280 + kvcol + c * 8);
#pragma unroll
    for (int e = 0; e < 8; ++e) {
      const int d = c * 8 + e;
      *(bf16_t*)((char*)Vt_lds + d * 256 + ((key * 2) ^ ((d & 7) << 4))) = v[e];
    }
  }
  for (int idx = tid; idx < 1024; idx += 256)
    *(bf16x8*)((char*)P_lds + idx * 16) = (bf16x8){};
  __syncthreads();

  const int l15 = lane & 15, hi = lane >> 4;
  const int dblk = hi << 3;
  const int prow0 = hi << 2;
  const float scale = 0.125f;
  char* const pw = (char*)P_lds[wid];

  const long qrow0 = (long)b * 4096 + ((long)blockIdx.x << 8) + (wid << 6);
  bf16x8 qf[4][2];
#pragma unroll
  for (int ms = 0; ms < 4; ++ms) {
    const bf16_t* qp = q + (qrow0 + ms * 16 + l15) * 1280 + kvcol;
    qf[ms][0] = ld16(qp + dblk);
    qf[ms][1] = ld16(qp + 32 + dblk);
  }

#pragma unroll
  for (int ms = 0; ms < 4; ++ms) {
    f32x4 sc[5];
#pragma unroll
    for (int t = 0; t < 5; ++t) {
      const int j = (t << 4) + l15;
      const bf16x8 k0 = ld16((char*)K_lds + j * 128 + ((hi ^ (j & 7)) << 4));
      const bf16x8 k1 = ld16((char*)K_lds + j * 128 + (((4 + hi) ^ (j & 7)) << 4));
      f32x4 z = {0.f, 0.f, 0.f, 0.f};
      z = __builtin_amdgcn_mfma_f32_16x16x32_bf16(qf[ms][0], k0, z, 0, 0, 0);
      z = __builtin_amdgcn_mfma_f32_16x16x32_bf16(qf[ms][1], k1, z, 0, 0, 0);
      sc[t] = z;
    }
#pragma unroll
    for (int t = 0; t < 5; ++t) {
      const bool valid = ((t << 4) + l15) < TXT_;
#pragma unroll
      for (int r = 0; r < 4; ++r)
        sc[t][r] = valid ? sc[t][r] * scale : -1e30f;
    }

#pragma unroll
    for (int r = 0; r < 4; ++r) {
      float m = sc[0][r];
#pragma unroll
      for (int t = 1; t < 5; ++t) m = fmaxf(m, sc[t][r]);
      m = fmaxf(m, __shfl_xor(m, 1));
      m = fmaxf(m, __shfl_xor(m, 2));
      m = fmaxf(m, __shfl_xor(m, 4));
      m = fmaxf(m, __shfl_xor(m, 8));
      float l = 0.f;
#pragma unroll
      for (int t = 0; t < 5; ++t) { const float p = __expf(sc[t][r] - m); sc[t][r] = p; l += p; }
      l += __shfl_xor(l, 1);
      l += __shfl_xor(l, 2);
      l += __shfl_xor(l, 4);
      l += __shfl_xor(l, 8);
      const float inv = 1.f / l;
      const int row = prow0 + r;
#pragma unroll
      for (int t = 0; t < 5; ++t)
        *(bf16_t*)(pw + row * 256 + ((((t << 4) + l15) * 2) ^ ((row & 7) << 4))) =
            (bf16_t)(sc[t][r] * inv);
    }

    {
      const bf16x8 ki0 = ld16((char*)Kip_lds + l15 * 128 + ((hi ^ (l15 & 7)) << 4));
      const bf16x8 ki1 = ld16((char*)Kip_lds + l15 * 128 + (((4 + hi) ^ (l15 & 7)) << 4));
      f32x4 z = {0.f, 0.f, 0.f, 0.f};
      z = __builtin_amdgcn_mfma_f32_16x16x32_bf16(qf[ms][0], ki0, z, 0, 0, 0);
      z = __builtin_amdgcn_mfma_f32_16x16x32_bf16(qf[ms][1], ki1, z, 0, 0, 0);
      const bool vip = l15 < 4;
#pragma unroll
      for (int r = 0; r < 4; ++r) {
        const float s = vip ? z[r] * scale : -1e30f;
        float m = s;
        m = fmaxf(m, __shfl_xor(m, 1));
        m = fmaxf(m, __shfl_xor(m, 2));
        m = fmaxf(m, __shfl_xor(m, 4));
        m = fmaxf(m, __shfl_xor(m, 8));
        const float p = __expf(s - m);
        float l = p;
        l += __shfl_xor(l, 1);
        l += __shfl_xor(l, 2);
        l += __shfl_xor(l, 4);
        l += __shfl_xor(l, 8);
        const int row = prow0 + r;
        *(bf16_t*)(pw + row * 256 + (((96 + l15) * 2) ^ ((row & 7) << 4))) =
            (bf16_t)(p * (1.f / l));
      }
    }

    f32x4 o[4] = {};
#pragma unroll
    for (int s = 0; s < 4; ++s) {
      const bf16x8 pa =
          ld16(pw + l15 * 256 + ((((s << 2) + hi) << 4) ^ ((l15 & 7) << 4)));
#pragma unroll
      for (int n = 0; n < 4; ++n) {
        const int d = (n << 4) + l15;
        const bf16x8 vb =
            ld16((char*)Vt_lds + d * 256 + ((((s << 2) + hi) << 4) ^ ((d & 7) << 4)));
        o[n] = __builtin_amdgcn_mfma_f32_16x16x32_bf16(pa, vb, o[n], 0, 0, 0);
      }
    }

    const long orow = qrow0 + ms * 16 + prow0;
#pragma unroll
    for (int n = 0; n < 4; ++n)
#pragma unroll
      for (int r = 0; r < 4; ++r)
        outp[(orow + r) * 1280 + kvcol + (n << 4) + l15] = (bf16_t)o[n][r];
  }
}

// ---------------------------------------------------------------------------
// Utility kernels
// ---------------------------------------------------------------------------
// merged weight transpose+cvt: z selects which weight; in K x 1280 fp32 ->
// out 1280 x K bf16 (row stride = K). Grid (64, 40, 6); z<2 has K=1280.
__global__ void transpose_all(const float* __restrict__ Wq, const float* __restrict__ Wo,
                              const float* __restrict__ Wk, const float* __restrict__ Wv,
                              const float* __restrict__ Wki, const float* __restrict__ Wvi,
                              bf16_t* __restrict__ Wq_t, bf16_t* __restrict__ Wo_t,
                              bf16_t* __restrict__ Wkv_t, bf16_t* __restrict__ Wip_t)
{
  const int z = blockIdx.z;
  const float* in;
  bf16_t* out;
  int K;
  switch (z) {
    case 0:  in = Wq;  out = Wq_t;                        K = 1280; break;
    case 1:  in = Wo;  out = Wo_t;                        K = 1280; break;
    case 2:  in = Wk;  out = Wkv_t;                       K = 2048; break;
    case 3:  in = Wv;  out = Wkv_t + (long)1280 * 2048;   K = 2048; break;
    case 4:  in = Wki; out = Wip_t;                       K = 2048; break;
    default: in = Wvi; out = Wip_t + (long)1280 * 2048;   K = 2048; break;
  }
  const int k0 = blockIdx.x * 32, n0 = blockIdx.y * 32;
  if (k0 >= K) return;
  __shared__ float tile[32][33];
  for (int i = threadIdx.y; i < 32; i += 8)
    tile[i][threadIdx.x] = in[(long)(k0 + i) * 1280 + n0 + threadIdx.x];
  __syncthreads();
  for (int i = threadIdx.y; i < 32; i += 8)
    out[(long)(n0 + i) * K + k0 + threadIdx.x] = (bf16_t)tile[threadIdx.x][i];
}

__global__ void pack_enc(const float* __restrict__ enc, bf16_t* __restrict__ a_txt,
                         bf16_t* __restrict__ a_ip)
{
  const long t4 = ((long)blockIdx.x * 256 + threadIdx.x) * 4;
  const long NTXT = 640L * 2048;
  bf16x4 r;
  r[0] = r[1] = r[2] = r[3] = (bf16_t)0.f;
  if (t4 < NTXT) {
    const int row = (int)(t4 >> 11), col = (int)(t4 & 2047);
    const int b = row / 80, j = row - b * 80;
    if (j < TXT_) {
      const float4 v = *(const float4*)(enc + (((long)(b * 81 + j)) << 11) + col);
      r[0] = (bf16_t)v.x; r[1] = (bf16_t)v.y; r[2] = (bf16_t)v.z; r[3] = (bf16_t)v.w;
    }
    *(bf16x4*)(a_txt + t4) = r;
  } else {
    const long u = t4 - NTXT;
    const int row = (int)(u >> 11), col = (int)(u & 2047);
    if (row < 32) {
      const int b = row >> 2, j = row & 3;
      const float4 v = *(const float4*)(enc + (((long)(b * 81 + TXT_ + j)) << 11) + col);
      r[0] = (bf16_t)v.x; r[1] = (bf16_t)v.y; r[2] = (bf16_t)v.z; r[3] = (bf16_t)v.w;
    }
    *(bf16x4*)(a_ip + u) = r;
  }
}

// ---------------------------------------------------------------------------
extern "C" void kernel_launch(void* const* d_in, const int* in_sizes, int n_in,
                              void* d_out, int out_size, void* d_ws, size_t ws_size,
                              hipStream_t stream)
{
  (void)in_sizes; (void)n_in; (void)out_size; (void)ws_size;
  const float* hs  = (const float*)d_in[0];
  const float* enc = (const float*)d_in[1];
  const float* Wq  = (const float*)d_in[2];
  const float* Wk  = (const float*)d_in[3];
  const float* Wv  = (const float*)d_in[4];
  const float* Wki = (const float*)d_in[5];
  const float* Wvi = (const float*)d_in[6];
  const float* Wo  = (const float*)d_in[7];
  const float* bo  = (const float*)d_in[8];

  char* ws = (char*)d_ws;
  size_t off = 0;
  auto alloc = [&](size_t bytes) {
    char* p = ws + off;
    off += (bytes + 255) & ~(size_t)255;
    return p;
  };
  bf16_t* qb     = (bf16_t*)alloc(83886080);  // Q (32768 x 1280), attn in-place
  bf16_t* Wq_t   = (bf16_t*)alloc(3276800);
  bf16_t* Wo_t   = (bf16_t*)alloc(3276800);
  bf16_t* Wkv_t  = (bf16_t*)alloc(10485760);
  bf16_t* Wip_t  = (bf16_t*)alloc(10485760);
  bf16_t* a_txt  = (bf16_t*)alloc(2621440);
  bf16_t* a_ip   = (bf16_t*)alloc(524288);
  bf16_t* kv_txt = (bf16_t*)alloc(3276800);
  bf16_t* kv_ip  = (bf16_t*)alloc(655360);

  transpose_all<<<dim3(64, 40, 6), dim3(32, 8), 0, stream>>>(
      Wq, Wo, Wk, Wv, Wki, Wvi, Wq_t, Wo_t, Wkv_t, Wip_t);
  pack_enc<<<1536, 256, 0, stream>>>(enc, a_txt, a_ip);

  // Q = cvt(hs_fp32) @ Wq  (A reg-staged from fp32 inside the GEMM; no cvt pass)
  gemm256<0, 1><<<640, 512, 0, stream>>>(hs, Wq_t, qb, 5, 1280, 1280,
                                         nullptr, nullptr);
  // K|V and Kip|Vip projections in one dispatch
  gemm_small<<<120, 256, 0, stream>>>(a_txt, Wkv_t, kv_txt, a_ip, Wip_t, kv_ip);

  // fused dual-softmax attention, in-place on qb
  attn_fused<<<dim3(16, 20, 8), 256, 0, stream>>>(qb, kv_txt, kv_ip, qb);

  // out = attn @ Wo + bo + residual(fp32 hs)
  gemm256<2, 0><<<640, 512, 0, stream>>>(qb, Wo_t, d_out, 5, 1280, 1280,
                                         bo, hs);
}

// Round 14
// 419.413 us; speedup vs baseline: 4.7103x; 1.1223x over previous
//
#include <hip/hip_runtime.h>
#include <hip/hip_bf16.h>
#include <cstdint>
#include <cstddef>

// ---------------------------------------------------------------------------
// IPAttnProcessor: out = (softmax(QK^T)V + softmax(QKip^T)Vip) @ Wo + bo + residual
// B=8 SQ=4096 C=1280 CAD=2048 H=20 D=64 TXT=77 NT=4 IP_SCALE=1
// GEMM core: r8 config (256^2, BK=32, ring-4 LDS 128KB, counted vmcnt(4),
// 16x16 MFMA, verified 0-conflict swizzle, LDS-packed bf16 epilogue).
// r14 = r13 + OOB fix in prep (a_ip pad rows 32..255 must not read enc:
// guard is row < 32 = B*NT, not row < 128). Launch structure: projections
// merged into GEMM1's dispatch; cvt/transpose/pack in one prep kernel.
// ---------------------------------------------------------------------------

typedef __bf16 bf16_t;
typedef __bf16 bf16x8 __attribute__((ext_vector_type(8)));
typedef __bf16 bf16x4 __attribute__((ext_vector_type(4)));
typedef float  f32x4  __attribute__((ext_vector_type(4)));
typedef unsigned int u32x4 __attribute__((ext_vector_type(4)));

using as3_void  = __attribute__((address_space(3))) void;
using as1_cvoid = const __attribute__((address_space(1))) void;

#define TXT_ 77

__device__ __forceinline__ bf16x8 ld16(const void* p) {
  u32x4 v = *(const u32x4*)p;
  return __builtin_bit_cast(bf16x8, v);
}

// ---------------------------------------------------------------------------
// r8-exact GEMM body: C[M,N] = A[M,K] @ Bt[N,K]^T. 256x256 tile, BK=32,
// 512 thr (8 waves = 2M x 4N, per-wave 128x64, acc[8][4]).
// LDS 128KB: A ring4 @0, B ring4 @64KB. K-tile t reads buf[t&3], stages t+2
// (race-free); tile-end s_waitcnt vmcnt(4) counted, drain at NTk-2.
// EPI=0: LDS-packed bf16 epilogue (512B full-line stores).
// EPI=2: f32 + bias[col] + bf16 residual (64B stores).
// ---------------------------------------------------------------------------
template <int EPI>
__device__ __forceinline__ void gemm256_body(
    char* smem, const bf16_t* __restrict__ A, const bf16_t* __restrict__ Bt,
    void* __restrict__ Cout, int g, int ntn, int N, int K,
    const float* __restrict__ bias, const bf16_t* __restrict__ residual)
{
  const int tid = threadIdx.x, lane = tid & 63, wid = tid >> 6;
  const int wm = wid >> 2, wn = wid & 3;

  const long bm = (long)(g / ntn) * 256;
  const long bn = (long)(g % ntn) * 256;
  const int NTk = K >> 5;

  const int srow = lane >> 2;
  const int scol = ((lane & 3) ^ ((lane >> 3) & 3)) * 8;

  auto stageA = [&](int t) {
    const int buf = t & 3;
    const long k0 = (long)t << 5;
#pragma unroll
    for (int j = 0; j < 2; ++j) {
      const int ci = j * 8 + wid;
      const bf16_t* gp = A + (bm + ci * 16 + srow) * (long)K + k0 + scol;
      __builtin_amdgcn_global_load_lds((as1_cvoid*)gp,
          (as3_void*)(smem + buf * 16384 + ci * 1024), 16, 0, 0);
    }
  };
  auto stageB = [&](int t) {
    const int buf = t & 3;
    const long k0 = (long)t << 5;
#pragma unroll
    for (int j = 0; j < 2; ++j) {
      const int ci = j * 8 + wid;
      const bf16_t* gp = Bt + (bn + ci * 16 + srow) * (long)K + k0 + scol;
      __builtin_amdgcn_global_load_lds((as1_cvoid*)gp,
          (as3_void*)(smem + 65536 + buf * 16384 + ci * 1024), 16, 0, 0);
    }
  };

  const int l15 = lane & 15, kq = lane >> 4;
  const int rc16 = (kq ^ ((l15 >> 1) & 3)) << 4;

  f32x4 acc[8][4] = {};
  bf16x8 afr[4], bfr[4];

  stageA(0); stageB(0); stageA(1); stageB(1);
  asm volatile("s_waitcnt vmcnt(4)" ::: "memory");
  __builtin_amdgcn_s_barrier();

  for (int t = 0; t < NTk; ++t) {
    const char* sa = smem + (t & 3) * 16384;
    const char* sb = smem + 65536 + (t & 3) * 16384;
    const bool pf = (t + 2 < NTk);

    // ---- P0: B all + A m0-3, stage A(t+2), MFMA upper half ----
#pragma unroll
    for (int n = 0; n < 4; ++n)
      bfr[n] = ld16(sb + (wn * 64 + n * 16 + l15) * 64 + rc16);
#pragma unroll
    for (int m = 0; m < 4; ++m)
      afr[m] = ld16(sa + (wm * 128 + m * 16 + l15) * 64 + rc16);
    if (pf) stageA(t + 2);
    __builtin_amdgcn_s_setprio(1);
#pragma unroll
    for (int m = 0; m < 4; ++m)
#pragma unroll
      for (int n = 0; n < 4; ++n)
        acc[m][n] = __builtin_amdgcn_mfma_f32_16x16x32_bf16(afr[m], bfr[n], acc[m][n], 0, 0, 0);
    __builtin_amdgcn_s_setprio(0);

    // ---- P1: A m4-7, stage B(t+2), MFMA lower half ----
#pragma unroll
    for (int m = 0; m < 4; ++m)
      afr[m] = ld16(sa + (wm * 128 + (m + 4) * 16 + l15) * 64 + rc16);
    if (pf) stageB(t + 2);
    __builtin_amdgcn_s_setprio(1);
#pragma unroll
    for (int m = 0; m < 4; ++m)
#pragma unroll
      for (int n = 0; n < 4; ++n)
        acc[m + 4][n] = __builtin_amdgcn_mfma_f32_16x16x32_bf16(afr[m], bfr[n], acc[m + 4][n], 0, 0, 0);
    __builtin_amdgcn_s_setprio(0);

    // ---- tile-end: counted wait ----
    if (t == NTk - 2) asm volatile("s_waitcnt vmcnt(0)" ::: "memory");
    else              asm volatile("s_waitcnt vmcnt(4)" ::: "memory");
    __builtin_amdgcn_s_barrier();
  }

  const int orow0 = (lane >> 4) << 2;
  if constexpr (EPI == 0) {
    // LDS-packed epilogue: acc -> smem bf16 [256][256], then 512B full-line sweeps
    bf16_t* cl = (bf16_t*)smem;
    const int lrow0 = wm * 128 + orow0;
    const int lcol0 = wn * 64 + l15;
#pragma unroll
    for (int m = 0; m < 8; ++m)
#pragma unroll
      for (int n = 0; n < 4; ++n)
#pragma unroll
        for (int r = 0; r < 4; ++r)
          cl[(lrow0 + m * 16 + r) * 256 + lcol0 + n * 16] = (bf16_t)acc[m][n][r];
    __syncthreads();
    const int rr = tid >> 5, cc = tid & 31;
#pragma unroll
    for (int s = 0; s < 16; ++s) {
      const int row = s * 16 + rr;
      const u32x4 v = *(const u32x4*)(cl + row * 256 + cc * 8);
      *(u32x4*)((bf16_t*)Cout + (bm + row) * (long)N + bn + cc * 8) = v;
    }
  } else {
#pragma unroll
    for (int m = 0; m < 8; ++m) {
#pragma unroll
      for (int n = 0; n < 4; ++n) {
        const long col = bn + wn * 64 + n * 16 + l15;
#pragma unroll
        for (int r = 0; r < 4; ++r) {
          const long row = bm + wm * 128 + m * 16 + orow0 + r;
          ((float*)Cout)[row * N + col] =
              acc[m][n][r] + bias[col] + (float)residual[row * N + col];
        }
      }
    }
  }
}

// GEMM1 + projections fused in one dispatch (680 blocks):
//   0-639:   Q = hs_bf16 @ Wq    (XCD-chunked swizzle over 640)
//   640-669: K|V = a_txt(768 pad) @ [Wk|Wv]   (3x10 tiles, K=2048)
//   670-679: Kip|Vip = a_ip(256 pad) @ [Wk_ip|Wv_ip] (1x10 tiles)
__global__ __launch_bounds__(512, 2)
void gemm1_fused(const bf16_t* __restrict__ hsb, const bf16_t* __restrict__ Wq_t,
                 bf16_t* __restrict__ qb,
                 const bf16_t* __restrict__ a_txt, const bf16_t* __restrict__ Wkv_t,
                 bf16_t* __restrict__ kv_txt,
                 const bf16_t* __restrict__ a_ip, const bf16_t* __restrict__ Wip_t,
                 bf16_t* __restrict__ kv_ip)
{
  __shared__ __align__(16) char smem[131072];
  const int bid = blockIdx.x;
  const bf16_t *A, *Bt;
  bf16_t* C;
  int g, ntn, N, K;
  if (bid < 640) {
    g = (bid & 7) * 80 + (bid >> 3);   // bijective on [0,640)
    A = hsb; Bt = Wq_t; C = qb; ntn = 5; N = 1280; K = 1280;
  } else if (bid < 670) {
    g = bid - 640; A = a_txt; Bt = Wkv_t; C = kv_txt; ntn = 10; N = 2560; K = 2048;
  } else {
    g = bid - 670; A = a_ip; Bt = Wip_t; C = kv_ip; ntn = 10; N = 2560; K = 2048;
  }
  gemm256_body<0>(smem, A, Bt, C, g, ntn, N, K, nullptr, nullptr);
}

// GEMM2: out = attn @ Wo + bo + residual(bf16), 640 blocks, XCD swizzle.
__global__ __launch_bounds__(512, 2)
void gemm2(const bf16_t* __restrict__ A, const bf16_t* __restrict__ Bt,
           float* __restrict__ Cout, const float* __restrict__ bias,
           const bf16_t* __restrict__ residual)
{
  __shared__ __align__(16) char smem[131072];
  const int bid = blockIdx.x;
  const int g = (bid & 7) * 80 + (bid >> 3);
  gemm256_body<2>(smem, A, Bt, Cout, g, 5, 1280, 1280, bias, residual);
}

// ---------------------------------------------------------------------------
// Fused attention (r8-unchanged; writes in-place over Q).
// ---------------------------------------------------------------------------
__global__ __launch_bounds__(256, 3)
void attn_fused(const bf16_t* __restrict__ q, const bf16_t* __restrict__ kvt,
                const bf16_t* __restrict__ kvip, bf16_t* __restrict__ outp)
{
  __shared__ __align__(16) bf16_t K_lds[80 * 64];
  __shared__ __align__(16) bf16_t Kip_lds[16 * 64];
  __shared__ __align__(16) bf16_t Vt_lds[64 * 128];
  __shared__ __align__(16) bf16_t P_lds[4][16 * 128];

  const int tid = threadIdx.x, lane = tid & 63, wid = tid >> 6;
  const int h = blockIdx.y, b = blockIdx.z;
  const int kvcol = h << 6;

  for (int idx = tid; idx < 640; idx += 256) {
    const int j = idx >> 3, c = idx & 7;
    bf16x8 v = {};
    if (j < TXT_) v = ld16(kvt + (long)(b * 80 + j) * 2560 + kvcol + c * 8);
    *(bf16x8*)((char*)K_lds + j * 128 + ((c ^ (j & 7)) << 4)) = v;
  }
  if (tid < 128) {
    const int j = tid >> 3, c = tid & 7;
    bf16x8 v = {};
    if (j < 4) v = ld16(kvip + (long)(b * 4 + j) * 2560 + kvcol + c * 8);
    *(bf16x8*)((char*)Kip_lds + j * 128 + ((c ^ (j & 7)) << 4)) = v;
  }
  for (int idx = tid; idx < 1024; idx += 256) {
    const int key = idx >> 3, c = idx & 7;
    bf16x8 v = {};
    if (key < TXT_)
      v = ld16(kvt + (long)(b * 80 + key) * 2560 + 1280 + kvcol + c * 8);
    else if (key >= 96 && key < 100)
      v = ld16(kvip + (long)(b * 4 + key - 96) * 2560 + 1280 + kvcol + c * 8);
#pragma unroll
    for (int e = 0; e < 8; ++e) {
      const int d = c * 8 + e;
      *(bf16_t*)((char*)Vt_lds + d * 256 + ((key * 2) ^ ((d & 7) << 4))) = v[e];
    }
  }
  for (int idx = tid; idx < 1024; idx += 256)
    *(bf16x8*)((char*)P_lds + idx * 16) = (bf16x8){};
  __syncthreads();

  const int l15 = lane & 15, hi = lane >> 4;
  const int dblk = hi << 3;
  const int prow0 = hi << 2;
  const float scale = 0.125f;
  char* const pw = (char*)P_lds[wid];

  const long qrow0 = (long)b * 4096 + ((long)blockIdx.x << 8) + (wid << 6);
  bf16x8 qf[4][2];
#pragma unroll
  for (int ms = 0; ms < 4; ++ms) {
    const bf16_t* qp = q + (qrow0 + ms * 16 + l15) * 1280 + kvcol;
    qf[ms][0] = ld16(qp + dblk);
    qf[ms][1] = ld16(qp + 32 + dblk);
  }

#pragma unroll
  for (int ms = 0; ms < 4; ++ms) {
    f32x4 sc[5];
#pragma unroll
    for (int t = 0; t < 5; ++t) {
      const int j = (t << 4) + l15;
      const bf16x8 k0 = ld16((char*)K_lds + j * 128 + ((hi ^ (j & 7)) << 4));
      const bf16x8 k1 = ld16((char*)K_lds + j * 128 + (((4 + hi) ^ (j & 7)) << 4));
      f32x4 z = {0.f, 0.f, 0.f, 0.f};
      z = __builtin_amdgcn_mfma_f32_16x16x32_bf16(qf[ms][0], k0, z, 0, 0, 0);
      z = __builtin_amdgcn_mfma_f32_16x16x32_bf16(qf[ms][1], k1, z, 0, 0, 0);
      sc[t] = z;
    }
#pragma unroll
    for (int t = 0; t < 5; ++t) {
      const bool valid = ((t << 4) + l15) < TXT_;
#pragma unroll
      for (int r = 0; r < 4; ++r)
        sc[t][r] = valid ? sc[t][r] * scale : -1e30f;
    }

#pragma unroll
    for (int r = 0; r < 4; ++r) {
      float m = sc[0][r];
#pragma unroll
      for (int t = 1; t < 5; ++t) m = fmaxf(m, sc[t][r]);
      m = fmaxf(m, __shfl_xor(m, 1));
      m = fmaxf(m, __shfl_xor(m, 2));
      m = fmaxf(m, __shfl_xor(m, 4));
      m = fmaxf(m, __shfl_xor(m, 8));
      float l = 0.f;
#pragma unroll
      for (int t = 0; t < 5; ++t) { const float p = __expf(sc[t][r] - m); sc[t][r] = p; l += p; }
      l += __shfl_xor(l, 1);
      l += __shfl_xor(l, 2);
      l += __shfl_xor(l, 4);
      l += __shfl_xor(l, 8);
      const float inv = 1.f / l;
      const int row = prow0 + r;
#pragma unroll
      for (int t = 0; t < 5; ++t)
        *(bf16_t*)(pw + row * 256 + ((((t << 4) + l15) * 2) ^ ((row & 7) << 4))) =
            (bf16_t)(sc[t][r] * inv);
    }

    {
      const bf16x8 ki0 = ld16((char*)Kip_lds + l15 * 128 + ((hi ^ (l15 & 7)) << 4));
      const bf16x8 ki1 = ld16((char*)Kip_lds + l15 * 128 + (((4 + hi) ^ (l15 & 7)) << 4));
      f32x4 z = {0.f, 0.f, 0.f, 0.f};
      z = __builtin_amdgcn_mfma_f32_16x16x32_bf16(qf[ms][0], ki0, z, 0, 0, 0);
      z = __builtin_amdgcn_mfma_f32_16x16x32_bf16(qf[ms][1], ki1, z, 0, 0, 0);
      const bool vip = l15 < 4;
#pragma unroll
      for (int r = 0; r < 4; ++r) {
        const float s = vip ? z[r] * scale : -1e30f;
        float m = s;
        m = fmaxf(m, __shfl_xor(m, 1));
        m = fmaxf(m, __shfl_xor(m, 2));
        m = fmaxf(m, __shfl_xor(m, 4));
        m = fmaxf(m, __shfl_xor(m, 8));
        const float p = __expf(s - m);
        float l = p;
        l += __shfl_xor(l, 1);
        l += __shfl_xor(l, 2);
        l += __shfl_xor(l, 4);
        l += __shfl_xor(l, 8);
        const int row = prow0 + r;
        *(bf16_t*)(pw + row * 256 + (((96 + l15) * 2) ^ ((row & 7) << 4))) =
            (bf16_t)(p * (1.f / l));
      }
    }

    f32x4 o[4] = {};
#pragma unroll
    for (int s = 0; s < 4; ++s) {
      const bf16x8 pa =
          ld16(pw + l15 * 256 + ((((s << 2) + hi) << 4) ^ ((l15 & 7) << 4)));
#pragma unroll
      for (int n = 0; n < 4; ++n) {
        const int d = (n << 4) + l15;
        const bf16x8 vb =
            ld16((char*)Vt_lds + d * 256 + ((((s << 2) + hi) << 4) ^ ((d & 7) << 4)));
        o[n] = __builtin_amdgcn_mfma_f32_16x16x32_bf16(pa, vb, o[n], 0, 0, 0);
      }
    }

    const long orow = qrow0 + ms * 16 + prow0;
#pragma unroll
    for (int n = 0; n < 4; ++n)
#pragma unroll
      for (int r = 0; r < 4; ++r)
        outp[(orow + r) * 1280 + kvcol + (n << 4) + l15] = (bf16_t)o[n][r];
  }
}

// ---------------------------------------------------------------------------
// prep: merged cvt_bf16 (blocks 0-40959) + weight transpose (40960-56319)
// + pack_enc with padding (56320-58367). All 256-thread, BW-bound.
// a_txt padded to 768 rows, a_ip to 256 rows (zeros) so projections run as
// integral 256^2 tiles inside gemm1_fused. Valid ip rows: 32 (=B*NT).
// ---------------------------------------------------------------------------
__global__ __launch_bounds__(256)
void prep(const float* __restrict__ hs, bf16_t* __restrict__ hsb,
          const float* __restrict__ Wq, const float* __restrict__ Wo,
          const float* __restrict__ Wk, const float* __restrict__ Wv,
          const float* __restrict__ Wki, const float* __restrict__ Wvi,
          bf16_t* __restrict__ Wq_t, bf16_t* __restrict__ Wo_t,
          bf16_t* __restrict__ Wkv_t, bf16_t* __restrict__ Wip_t,
          const float* __restrict__ enc, bf16_t* __restrict__ a_txt,
          bf16_t* __restrict__ a_ip)
{
  __shared__ float tile[32][33];
  const int bid = blockIdx.x, tid = threadIdx.x;

  if (bid < 40960) {                       // hs fp32 -> bf16 (41943040 elems)
    const long i = ((long)bid * 256 + tid) * 4;
    const float4 v = *(const float4*)(hs + i);
    bf16x4 r;
    r[0] = (bf16_t)v.x; r[1] = (bf16_t)v.y; r[2] = (bf16_t)v.z; r[3] = (bf16_t)v.w;
    *(bf16x4*)(hsb + i) = r;
  } else if (bid < 56320) {                // weight transpose+cvt (6 weights)
    const int idx = bid - 40960;
    const int z = idx / 2560, rem = idx % 2560;
    const int kx = rem & 63, ny = rem >> 6; // 64 k-tiles x 40 n-tiles
    const float* in;
    bf16_t* out;
    int K;
    switch (z) {
      case 0:  in = Wq;  out = Wq_t;                      K = 1280; break;
      case 1:  in = Wo;  out = Wo_t;                      K = 1280; break;
      case 2:  in = Wk;  out = Wkv_t;                     K = 2048; break;
      case 3:  in = Wv;  out = Wkv_t + (long)1280 * 2048; K = 2048; break;
      case 4:  in = Wki; out = Wip_t;                     K = 2048; break;
      default: in = Wvi; out = Wip_t + (long)1280 * 2048; K = 2048; break;
    }
    const int k0 = kx * 32, n0 = ny * 32;
    if (k0 < K) {
      const int tx = tid & 31, ty = tid >> 5;
      for (int i = ty; i < 32; i += 8)
        tile[i][tx] = in[(long)(k0 + i) * 1280 + n0 + tx];
      __syncthreads();
      for (int i = ty; i < 32; i += 8)
        out[(long)(n0 + i) * K + k0 + tx] = (bf16_t)tile[tx][i];
    }
  } else {                                 // encoder pack + zero-pad
    const long t4 = ((long)(bid - 56320) * 256 + tid) * 4;
    const long NTXT = 768L * 2048;
    bf16x4 r;
    r[0] = r[1] = r[2] = r[3] = (bf16_t)0.f;
    if (t4 < NTXT) {
      const int row = (int)(t4 >> 11), col = (int)(t4 & 2047);
      if (row < 640) {
        const int b = row / 80, j = row - b * 80;
        if (j < TXT_) {
          const float4 v = *(const float4*)(enc + (((long)(b * 81 + j)) << 11) + col);
          r[0] = (bf16_t)v.x; r[1] = (bf16_t)v.y; r[2] = (bf16_t)v.z; r[3] = (bf16_t)v.w;
        }
      }
      *(bf16x4*)(a_txt + t4) = r;
    } else {
      const long u = t4 - NTXT;
      const int row = (int)(u >> 11), col = (int)(u & 2047);
      if (row < 32) {                      // ONLY B*NT=32 valid ip rows
        const int b = row >> 2, j = row & 3;
        const float4 v = *(const float4*)(enc + (((long)(b * 81 + TXT_ + j)) << 11) + col);
        r[0] = (bf16_t)v.x; r[1] = (bf16_t)v.y; r[2] = (bf16_t)v.z; r[3] = (bf16_t)v.w;
      }
      *(bf16x4*)(a_ip + u) = r;
    }
  }
}

// ---------------------------------------------------------------------------
extern "C" void kernel_launch(void* const* d_in, const int* in_sizes, int n_in,
                              void* d_out, int out_size, void* d_ws, size_t ws_size,
                              hipStream_t stream)
{
  (void)in_sizes; (void)n_in; (void)out_size; (void)ws_size;
  const float* hs  = (const float*)d_in[0];
  const float* enc = (const float*)d_in[1];
  const float* Wq  = (const float*)d_in[2];
  const float* Wk  = (const float*)d_in[3];
  const float* Wv  = (const float*)d_in[4];
  const float* Wki = (const float*)d_in[5];
  const float* Wvi = (const float*)d_in[6];
  const float* Wo  = (const float*)d_in[7];
  const float* bo  = (const float*)d_in[8];

  char* ws = (char*)d_ws;
  size_t off = 0;
  auto alloc = [&](size_t bytes) {
    char* p = ws + off;
    off += (bytes + 255) & ~(size_t)255;
    return p;
  };
  bf16_t* buf1   = (bf16_t*)alloc(83886080);  // hs_bf16 (A of GEMM1 + residual of GEMM2)
  bf16_t* qb     = (bf16_t*)alloc(83886080);  // Q (32768 x 1280), attn in-place
  bf16_t* Wq_t   = (bf16_t*)alloc(3276800);
  bf16_t* Wo_t   = (bf16_t*)alloc(3276800);
  bf16_t* Wkv_t  = (bf16_t*)alloc(10485760);
  bf16_t* Wip_t  = (bf16_t*)alloc(10485760);
  bf16_t* a_txt  = (bf16_t*)alloc(3145728);   // 768 x 2048 (padded)
  bf16_t* a_ip   = (bf16_t*)alloc(1048576);   // 256 x 2048 (padded)
  bf16_t* kv_txt = (bf16_t*)alloc(3932160);   // 768 x 2560
  bf16_t* kv_ip  = (bf16_t*)alloc(1310720);   // 256 x 2560

  // one merged preprocessing dispatch
  prep<<<58368, 256, 0, stream>>>(hs, buf1, Wq, Wo, Wk, Wv, Wki, Wvi,
                                  Wq_t, Wo_t, Wkv_t, Wip_t, enc, a_txt, a_ip);

  // GEMM1 + K|V + Kip|Vip in one dispatch (680 blocks)
  gemm1_fused<<<680, 512, 0, stream>>>(buf1, Wq_t, qb,
                                       a_txt, Wkv_t, kv_txt,
                                       a_ip, Wip_t, kv_ip);

  // fused dual-softmax attention, in-place on qb
  attn_fused<<<dim3(16, 20, 8), 256, 0, stream>>>(qb, kv_txt, kv_ip, qb);

  // out = attn @ Wo + bo + residual(bf16)
  gemm2<<<640, 512, 0, stream>>>(qb, Wo_t, (float*)d_out, bo, buf1);
}